// Round 8
// baseline (4396.190 us; speedup 1.0000x reference)
//
#include <hip/hip_runtime.h>

typedef _Float16 h8 __attribute__((ext_vector_type(8)));
typedef float f32x4 __attribute__((ext_vector_type(4)));

__device__ __forceinline__ float fsigm(float x) {
    return __builtin_amdgcn_rcpf(1.0f + __expf(-x));
}
__device__ __forceinline__ float ftanh(float x) {
    float ax = fabsf(x);
    float e  = __expf(-2.0f * ax);
    float r  = (1.0f - e) * __builtin_amdgcn_rcpf(1.0f + e);
    return copysignf(r, x);
}
// LDS-only barrier: drains lgkmcnt, leaves global loads/stores in flight.
__device__ __forceinline__ void lds_barrier() {
    asm volatile("s_waitcnt lgkmcnt(0)\n\ts_barrier" ::: "memory");
}
// Device-scope grid barrier (sense via generation counter). All 256 blocks
// are co-resident (256 blocks x 512 thr, <=26KB LDS, <=256 VGPR: every CU can
// hold >=1, chip holds >=2x the grid), so spinning is deadlock-free.
__device__ __forceinline__ void gbar(unsigned int* cnt, unsigned int* gen,
                                     unsigned int nb) {
    __syncthreads();
    if (threadIdx.x == 0) {
        unsigned int g = __hip_atomic_load(gen, __ATOMIC_ACQUIRE, __HIP_MEMORY_SCOPE_AGENT);
        unsigned int t = __hip_atomic_fetch_add(cnt, 1u, __ATOMIC_ACQ_REL, __HIP_MEMORY_SCOPE_AGENT);
        if (t == nb - 1u) {
            __hip_atomic_store(cnt, 0u, __ATOMIC_RELAXED, __HIP_MEMORY_SCOPE_AGENT);
            __hip_atomic_fetch_add(gen, 1u, __ATOMIC_ACQ_REL, __HIP_MEMORY_SCOPE_AGENT);
        } else {
            while (__hip_atomic_load(gen, __ATOMIC_ACQUIRE, __HIP_MEMORY_SCOPE_AGENT) == g)
                __builtin_amdgcn_s_sleep(2);
        }
    }
    __syncthreads();
}

// ---------------------------------------------------------------------------
// K1: dist[256][8192] = input[256][512] @ akey[8192][512]^T   (NT GEMM, fp32)
// ---------------------------------------------------------------------------
__global__ __launch_bounds__(256) void k_dist(const float* __restrict__ A,
                                              const float* __restrict__ Bm,
                                              float* __restrict__ C) {
    __shared__ float As[32][68];
    __shared__ float Bs[32][132];
    const int n0 = blockIdx.x * 128;
    const int m0 = blockIdx.y * 64;
    const int tid = threadIdx.x;
    const int tx = tid & 15;
    const int ty = tid >> 4;
    const int lm = tid >> 3;
    const int lk = (tid & 7) * 4;
    float acc[4][8];
#pragma unroll
    for (int i = 0; i < 4; ++i)
#pragma unroll
        for (int j = 0; j < 8; ++j) acc[i][j] = 0.0f;

    for (int kt = 0; kt < 512; kt += 32) {
        __syncthreads();
#pragma unroll
        for (int r = 0; r < 2; ++r) {
            int m = lm + 32 * r;
            float4 v = *(const float4*)&A[(size_t)(m0 + m) * 512 + kt + lk];
            As[lk + 0][m] = v.x; As[lk + 1][m] = v.y;
            As[lk + 2][m] = v.z; As[lk + 3][m] = v.w;
        }
#pragma unroll
        for (int r = 0; r < 4; ++r) {
            int n = lm + 32 * r;
            float4 v = *(const float4*)&Bm[(size_t)(n0 + n) * 512 + kt + lk];
            Bs[lk + 0][n] = v.x; Bs[lk + 1][n] = v.y;
            Bs[lk + 2][n] = v.z; Bs[lk + 3][n] = v.w;
        }
        __syncthreads();
#pragma unroll
        for (int k = 0; k < 32; ++k) {
            float4 a4 = *(const float4*)&As[k][ty * 4];
            float4 b0 = *(const float4*)&Bs[k][tx * 8];
            float4 b1 = *(const float4*)&Bs[k][tx * 8 + 4];
            float av[4] = {a4.x, a4.y, a4.z, a4.w};
            float bv[8] = {b0.x, b0.y, b0.z, b0.w, b1.x, b1.y, b1.z, b1.w};
#pragma unroll
            for (int i = 0; i < 4; ++i)
#pragma unroll
                for (int j = 0; j < 8; ++j)
                    acc[i][j] = fmaf(av[i], bv[j], acc[i][j]);
        }
    }
#pragma unroll
    for (int i = 0; i < 4; ++i) {
        size_t row = (size_t)(m0 + ty * 4 + i) * 8192 + n0 + tx * 8;
        *(float4*)&C[row]     = make_float4(acc[i][0], acc[i][1], acc[i][2], acc[i][3]);
        *(float4*)&C[row + 4] = make_float4(acc[i][4], acc[i][5], acc[i][6], acc[i][7]);
    }
}

// ---------------------------------------------------------------------------
// K2: per-row argmax (first index on ties) -> set 0 -> softmax, in place
// ---------------------------------------------------------------------------
__global__ __launch_bounds__(256) void k_softmax(float* __restrict__ D) {
    __shared__ float row[8192];
    __shared__ float rv[256];
    __shared__ int   ri[256];
    const int b = blockIdx.x, tid = threadIdx.x;
    float* dr = D + (size_t)b * 8192;
    for (int i = tid; i < 2048; i += 256)
        *(float4*)&row[i * 4] = *(const float4*)&dr[i * 4];
    __syncthreads();

    float bv = -INFINITY; int bi = 0x7fffffff;
    for (int i = tid; i < 8192; i += 256) {
        float v = row[i];
        if (v > bv || (v == bv && i < bi)) { bv = v; bi = i; }
    }
    rv[tid] = bv; ri[tid] = bi;
    __syncthreads();
    for (int s = 128; s > 0; s >>= 1) {
        if (tid < s) {
            float ov = rv[tid + s]; int oi = ri[tid + s];
            if (ov > rv[tid] || (ov == rv[tid] && oi < ri[tid])) { rv[tid] = ov; ri[tid] = oi; }
        }
        __syncthreads();
    }
    if (tid == 0) row[ri[0]] = 0.0f;
    __syncthreads();

    float m = -INFINITY;
    for (int i = tid; i < 8192; i += 256) m = fmaxf(m, row[i]);
    rv[tid] = m;
    __syncthreads();
    for (int s = 128; s > 0; s >>= 1) {
        if (tid < s) rv[tid] = fmaxf(rv[tid], rv[tid + s]);
        __syncthreads();
    }
    const float M = rv[0];
    __syncthreads();

    float ssum = 0.0f;
    for (int i = tid; i < 8192; i += 256) {
        float e = __expf(row[i] - M);
        row[i] = e;
        ssum += e;
    }
    rv[tid] = ssum;
    __syncthreads();
    for (int s = 128; s > 0; s >>= 1) {
        if (tid < s) rv[tid] += rv[tid + s];
        __syncthreads();
    }
    const float inv = 1.0f / rv[0];
    for (int i = tid; i < 2048; i += 256) {
        float4 v = *(float4*)&row[i * 4];
        v.x *= inv; v.y *= inv; v.z *= inv; v.w *= inv;
        *(float4*)&dr[i * 4] = v;
    }
}

// ---------------------------------------------------------------------------
// K3: hist[256][544] += a[256][8192] @ aval[8192][544]  (NN GEMM, split-K=8)
// ---------------------------------------------------------------------------
__global__ __launch_bounds__(256) void k_hist(const float* __restrict__ A,
                                              const float* __restrict__ Bm,
                                              float* __restrict__ C) {
    __shared__ float As[32][68];
    __shared__ float Bs[32][68];
    const int n0 = blockIdx.x * 64;
    const int m0 = blockIdx.y * 64;
    const int kz = blockIdx.z;
    const int tid = threadIdx.x;
    const int tx = tid & 15, ty = tid >> 4;
    const int lr = tid >> 3;
    const int lq = (tid & 7) * 4;
    float acc[4][4];
#pragma unroll
    for (int i = 0; i < 4; ++i)
#pragma unroll
        for (int j = 0; j < 4; ++j) acc[i][j] = 0.0f;

    const int k_lo = kz * 1024, k_hi = k_lo + 1024;
    for (int kt = k_lo; kt < k_hi; kt += 32) {
        __syncthreads();
#pragma unroll
        for (int r = 0; r < 2; ++r) {
            int m = lr + 32 * r;
            float4 v = *(const float4*)&A[(size_t)(m0 + m) * 8192 + kt + lq];
            As[lq + 0][m] = v.x; As[lq + 1][m] = v.y;
            As[lq + 2][m] = v.z; As[lq + 3][m] = v.w;
        }
#pragma unroll
        for (int r = 0; r < 2; ++r) {
            int kk = (tid >> 4) + 16 * r;
            int nq = (tid & 15) * 4;
            float4 v = make_float4(0.f, 0.f, 0.f, 0.f);
            if (n0 + nq < 544)
                v = *(const float4*)&Bm[(size_t)(kt + kk) * 544 + n0 + nq];
            *(float4*)&Bs[kk][nq] = v;
        }
        __syncthreads();
#pragma unroll
        for (int k = 0; k < 32; ++k) {
            float4 a4 = *(const float4*)&As[k][ty * 4];
            float4 b4 = *(const float4*)&Bs[k][tx * 4];
            float av[4] = {a4.x, a4.y, a4.z, a4.w};
            float bv[4] = {b4.x, b4.y, b4.z, b4.w};
#pragma unroll
            for (int i = 0; i < 4; ++i)
#pragma unroll
                for (int j = 0; j < 4; ++j)
                    acc[i][j] = fmaf(av[i], bv[j], acc[i][j]);
        }
    }
#pragma unroll
    for (int i = 0; i < 4; ++i)
#pragma unroll
        for (int j = 0; j < 4; ++j) {
            int n = n0 + tx * 4 + j;
            if (n < 544)
                atomicAdd(&C[(size_t)(m0 + ty * 4 + i) * 544 + n], acc[i][j]);
        }
}

// ---------------------------------------------------------------------------
// K4: x[b][t][o] = tanh(b1[o] + W1[o][0]*input[b][t] + sum_j W1[o][1+j]*hist[b][t+j])
// ---------------------------------------------------------------------------
__global__ __launch_bounds__(256) void k_xfeat(const float* __restrict__ inp,
                                               const float* __restrict__ hist,
                                               const float* __restrict__ W1,
                                               const float* __restrict__ b1,
                                               float* __restrict__ X) {
    __shared__ float w[33 * 64];
    __shared__ float bl[64];
    __shared__ float il[128];
    __shared__ float hl[160];
    const int t0 = blockIdx.x * 128;
    const int b  = blockIdx.y;
    const int tid = threadIdx.x;
    for (int idx = tid; idx < 2112; idx += 256) {
        int o = idx / 33, k = idx % 33;
        w[k * 64 + o] = W1[idx];
    }
    if (tid < 64) bl[tid] = b1[tid];
    if (tid < 128) il[tid] = inp[(size_t)b * 512 + t0 + tid];
    for (int i = tid; i < 159; i += 256) hl[i] = hist[(size_t)b * 544 + t0 + i];
    __syncthreads();
    const int o = tid & 63, tq = tid >> 6;
    for (int it = 0; it < 32; ++it) {
        int tl = it * 4 + tq;
        float acc = fmaf(il[tl], w[o], bl[o]);
#pragma unroll
        for (int j = 0; j < 32; ++j)
            acc = fmaf(hl[tl + j], w[(1 + j) * 64 + o], acc);
        X[(size_t)(b * 512 + t0 + tl) * 64 + o] = ftanh(acc);
    }
}

// ---------------------------------------------------------------------------
// Pre-gate GEMM body, 512 threads, tile 64(m) x 128(n) x 32(k).
// ---------------------------------------------------------------------------
template <int K>
__device__ __forceinline__ void pregemm_body(const float* __restrict__ A,
                                             const float* __restrict__ Bw,
                                             const float* __restrict__ bih,
                                             const float* __restrict__ bhh,
                                             float* __restrict__ C,
                                             int t0, int tcs, int gb, float* sm) {
    float* As = sm;             // [32][68]
    float* Bs = sm + 32 * 68;   // [32][132]
    const int n0 = (gb & 3) * 128;
    const int m0 = (gb >> 2) * 64;
    const int tid = threadIdx.x;
    const int tx = tid & 31;
    const int ty = tid >> 5;
    const int lm = tid >> 3;
    const int lk = (tid & 7) * 4;
    const int ln = tid >> 2;
    const int lkb = (tid & 3) * 8;
    const int tcm = (1 << tcs) - 1;
    float acc[4][4];
#pragma unroll
    for (int i = 0; i < 4; ++i)
#pragma unroll
        for (int j = 0; j < 4; ++j) acc[i][j] = 0.0f;

    for (int kt = 0; kt < K; kt += 32) {
        __syncthreads();
        {
            int m = m0 + lm;
            size_t arow = (size_t)(m >> tcs) * 512 + t0 + (m & tcm);
            float4 v = *(const float4*)&A[arow * K + kt + lk];
            As[(lk + 0) * 68 + lm] = v.x; As[(lk + 1) * 68 + lm] = v.y;
            As[(lk + 2) * 68 + lm] = v.z; As[(lk + 3) * 68 + lm] = v.w;
        }
        {
            const float* bp = &Bw[(size_t)(n0 + ln) * K + kt + lkb];
            float4 v0 = *(const float4*)bp;
            float4 v1 = *(const float4*)(bp + 4);
            Bs[(lkb + 0) * 132 + ln] = v0.x; Bs[(lkb + 1) * 132 + ln] = v0.y;
            Bs[(lkb + 2) * 132 + ln] = v0.z; Bs[(lkb + 3) * 132 + ln] = v0.w;
            Bs[(lkb + 4) * 132 + ln] = v1.x; Bs[(lkb + 5) * 132 + ln] = v1.y;
            Bs[(lkb + 6) * 132 + ln] = v1.z; Bs[(lkb + 7) * 132 + ln] = v1.w;
        }
        __syncthreads();
#pragma unroll
        for (int k = 0; k < 32; ++k) {
            float4 a4 = *(const float4*)&As[k * 68 + ty * 4];
            float4 b4 = *(const float4*)&Bs[k * 132 + tx * 4];
            float av[4] = {a4.x, a4.y, a4.z, a4.w};
            float bv[4] = {b4.x, b4.y, b4.z, b4.w};
#pragma unroll
            for (int i = 0; i < 4; ++i)
#pragma unroll
                for (int j = 0; j < 4; ++j)
                    acc[i][j] = fmaf(av[i], bv[j], acc[i][j]);
        }
    }
    float bb[4];
#pragma unroll
    for (int j = 0; j < 4; ++j) {
        int n = n0 + tx * 4 + j;
        bb[j] = bih[n] + bhh[n];
    }
#pragma unroll
    for (int i = 0; i < 4; ++i) {
        size_t row = (size_t)(m0 + ty * 4 + i) * 512 + n0 + tx * 4;
        *(float4*)&C[row] = make_float4(acc[i][0] + bb[0], acc[i][1] + bb[1],
                                        acc[i][2] + bb[2], acc[i][3] + bb[3]);
    }
}

#define HPROW(hpb, buf, pl, m) ((_Float16*)((hpb) + ((((buf)*2 + (pl))*16 + (m)) * 72)))

// ---------------------------------------------------------------------------
// One t-chunk of the MFMA LSTM recurrence; persistent state (c, weight frags,
// h planes in LDS) lives across calls. Lane-local gates as round 6/7.
// ---------------------------------------------------------------------------
__device__ __forceinline__ void rec_chunk(const float* __restrict__ P,
                                          float* __restrict__ Hout,
                                          float* __restrict__ Sfin,
                                          int t0, int TC, int b0,
                                          float c[4],
                                          const h8 (&bh)[4][4], const h8 (&bl)[4][4],
                                          const int (&off)[4][4],
                                          unsigned int* hpb) {
    const int tid  = threadIdx.x;
    const int lane = tid & 63;
    const int wv   = tid >> 6;
    const int quad = lane >> 4;
    const int l15  = lane & 15;
    const int hu   = wv * 16 + l15;

    float pc[4][4];
#pragma unroll
    for (int g = 0; g < 4; ++g)
#pragma unroll
        for (int r = 0; r < 4; ++r)
            pc[g][r] = P[off[g][r]];

    const bool wr = (Hout != nullptr);
    const float* Pn = P + 512;
    float* Ho = wr ? (Hout + (size_t)t0 * 128) : nullptr;

    for (int tl = 0; tl < TC; ++tl) {
        float pn[4][4];
#pragma unroll
        for (int g = 0; g < 4; ++g)
#pragma unroll
            for (int r = 0; r < 4; ++r)
                pn[g][r] = Pn[off[g][r]];

        const int rb = tl & 1;
        h8 ah[4], al[4];
#pragma unroll
        for (int q = 0; q < 4; ++q) {
            int hoff = 32 * q + 8 * quad;
            ah[q] = *(const h8*)&HPROW(hpb, rb, 0, l15)[hoff];
            al[q] = *(const h8*)&HPROW(hpb, rb, 1, l15)[hoff];
        }

        f32x4 acc[4];
#pragma unroll
        for (int g = 0; g < 4; ++g) {
            acc[g][0] = pc[g][0]; acc[g][1] = pc[g][1];
            acc[g][2] = pc[g][2]; acc[g][3] = pc[g][3];
        }
#pragma unroll
        for (int q = 0; q < 4; ++q) {
#pragma unroll
            for (int g = 0; g < 4; ++g) {
                acc[g] = __builtin_amdgcn_mfma_f32_16x16x32_f16(ah[q], bh[g][q], acc[g], 0, 0, 0);
                acc[g] = __builtin_amdgcn_mfma_f32_16x16x32_f16(al[q], bh[g][q], acc[g], 0, 0, 0);
                acc[g] = __builtin_amdgcn_mfma_f32_16x16x32_f16(ah[q], bl[g][q], acc[g], 0, 0, 0);
            }
        }

        const int wb = (tl + 1) & 1;
#pragma unroll
        for (int r = 0; r < 4; ++r) {
            int m = quad * 4 + r;
            float iv = fsigm(acc[0][r]);
            float fv = fsigm(acc[1][r]);
            float gv = ftanh(acc[2][r]);
            float ov = fsigm(acc[3][r]);
            c[r] = fv * c[r] + iv * gv;
            float h = ov * ftanh(c[r]);
            _Float16 hh = (_Float16)h;
            HPROW(hpb, wb, 0, m)[hu] = hh;
            HPROW(hpb, wb, 1, m)[hu] = (_Float16)(h - (float)hh);
            if (wr) Ho[((size_t)(b0 + m) * 512 + tl) * 128 + hu] = h;
            if (Sfin && tl == TC - 1) Sfin[(size_t)(b0 + m) * 128 + hu] = h;
        }
        lds_barrier();

        Pn += 512;
#pragma unroll
        for (int g = 0; g < 4; ++g)
#pragma unroll
            for (int r = 0; r < 4; ++r)
                pc[g][r] = pn[g][r];
    }
}

// ---------------------------------------------------------------------------
// K5: persistent pipelined network. 256 blocks x 512 threads (all co-resident).
// Blocks 0-15: rec0 (chunk k). 16-31: rec1 (chunk k-2). 32-255: GEMM workers
// (pre0 chunk k+1, pre1 chunk k-1). Grid barrier + device fences between
// stages; weights/state persist in registers/LDS for the whole sequence.
// ---------------------------------------------------------------------------
struct PipeArgs {
    const float* X; float* H0;
    const float* Wih0; const float* Wih1;
    const float* bih0; const float* bhh0;
    const float* bih1; const float* bhh1;
    const float* Whh0; const float* Whh1;
    float* P0a; float* P0b; float* P1a; float* P1b;
    float* S1;
    unsigned int* cnt; unsigned int* gen;
    int TC; int tcs; int NC;
};

__global__ __launch_bounds__(512, 2) void k_pipe(PipeArgs a) {
    __shared__ float smem[6400];   // rec: 18.4 KB h planes; workers: 25.6 KB staging
    unsigned int* hpb = (unsigned int*)smem;
    const int bid = blockIdx.x;
    const int tid = threadIdx.x;
    const int TC = a.TC, NC = a.NC;

    h8 bh[4][4], bl[4][4];
    float c[4] = {0.f, 0.f, 0.f, 0.f};
    int off[4][4];
    int b0 = 0;

    if (bid < 32) {
        const int lane = tid & 63;
        const int wv   = tid >> 6;
        const int quad = lane >> 4;
        const int l15  = lane & 15;
        const int hu   = wv * 16 + l15;
        b0 = (bid & 15) * 16;
        const float* Whh = (bid < 16) ? a.Whh0 : a.Whh1;
#pragma unroll
        for (int g = 0; g < 4; ++g) {
            int n = g * 128 + hu;
#pragma unroll
            for (int q = 0; q < 4; ++q) {
                int kb = q * 32 + quad * 8;
                const float* wp = &Whh[(size_t)n * 128 + kb];
                float4 w0 = *(const float4*)wp;
                float4 w1 = *(const float4*)(wp + 4);
                float we[8] = {w0.x, w0.y, w0.z, w0.w, w1.x, w1.y, w1.z, w1.w};
#pragma unroll
                for (int j = 0; j < 8; ++j) {
                    _Float16 hi = (_Float16)we[j];
                    bh[g][q][j] = hi;
                    bl[g][q][j] = (_Float16)(we[j] - (float)hi);
                }
            }
        }
#pragma unroll
        for (int g = 0; g < 4; ++g)
#pragma unroll
            for (int r = 0; r < 4; ++r)
                off[g][r] = (b0 + quad * 4 + r) * TC * 512 + g * 128 + hu;
        // zero h planes (buffer 0)
#pragma unroll
        for (int r = 0; r < 4; ++r) {
            int m = quad * 4 + r;
            HPROW(hpb, 0, 0, m)[hu] = (_Float16)0.f;
            HPROW(hpb, 0, 1, m)[hu] = (_Float16)0.f;
        }
    }

    for (int k = -1; k <= NC + 1; ++k) {
        if (bid < 16) {
            if (k >= 0 && k < NC)
                rec_chunk((k & 1) ? a.P0b : a.P0a, a.H0, nullptr,
                          k * TC, TC, b0, c, bh, bl, off, hpb);
        } else if (bid < 32) {
            int ck = k - 2;
            if (ck >= 0 && ck < NC)
                rec_chunk((ck & 1) ? a.P1b : a.P1a, nullptr,
                          (ck == NC - 1) ? a.S1 : nullptr,
                          ck * TC, TC, b0, c, bh, bl, off, hpb);
        } else {
            const int wj = bid - 32;
            const int njobs = (256 * TC / 64) * 4;
            int c0 = k + 1;
            if (c0 >= 0 && c0 < NC) {
                float* P0w = (c0 & 1) ? a.P0b : a.P0a;
                for (int j = wj; j < njobs; j += 224)
                    pregemm_body<64>(a.X, a.Wih0, a.bih0, a.bhh0, P0w, c0 * TC, a.tcs, j, smem);
            }
            int c1 = k - 1;
            if (c1 >= 0 && c1 < NC) {
                float* P1w = (c1 & 1) ? a.P1b : a.P1a;
                for (int j = wj; j < njobs; j += 224)
                    pregemm_body<128>(a.H0, a.Wih1, a.bih1, a.bhh1, P1w, c1 * TC, a.tcs, j, smem);
            }
        }
        __threadfence();                 // release P/H0 writes to device scope
        gbar(a.cnt, a.gen, 256u);
        __threadfence();                 // acquire (invalidate stale caches)
    }
}

// ---------------------------------------------------------------------------
// K6: tail head: out = tanh(tanh(h1_last) @ W2^T + b2) @ W3^T + b3
// ---------------------------------------------------------------------------
__global__ __launch_bounds__(64) void k_tail(const float* __restrict__ Hs,
                                             const float* __restrict__ W2,
                                             const float* __restrict__ b2,
                                             const float* __restrict__ W3,
                                             const float* __restrict__ b3,
                                             float* __restrict__ out) {
    __shared__ float last[128], l2s[64];
    const int b = blockIdx.x, tid = threadIdx.x;
    last[tid]      = ftanh(Hs[(size_t)b * 128 + tid]);
    last[tid + 64] = ftanh(Hs[(size_t)b * 128 + 64 + tid]);
    __syncthreads();
    float acc = b2[tid];
#pragma unroll 4
    for (int j = 0; j < 128; ++j) acc = fmaf(W2[(size_t)tid * 128 + j], last[j], acc);
    l2s[tid] = ftanh(acc);
    __syncthreads();
    if (tid < 32) {
        float a2 = b3[tid];
#pragma unroll 4
        for (int o = 0; o < 64; ++o) a2 = fmaf(W3[(size_t)tid * 64 + o], l2s[o], a2);
        out[(size_t)b * 32 + tid] = a2;
    }
}

// ---------------------------------------------------------------------------
extern "C" void kernel_launch(void* const* d_in, const int* in_sizes, int n_in,
                              void* d_out, int out_size, void* d_ws, size_t ws_size,
                              hipStream_t stream) {
    (void)in_sizes; (void)n_in; (void)out_size;
    const float* inp  = (const float*)d_in[0];
    const float* akey = (const float*)d_in[1];
    const float* aval = (const float*)d_in[2];
    const float* W1   = (const float*)d_in[3];
    const float* b1   = (const float*)d_in[4];
    const float* Wih0 = (const float*)d_in[5];
    const float* Whh0 = (const float*)d_in[6];
    const float* bih0 = (const float*)d_in[7];
    const float* bhh0 = (const float*)d_in[8];
    const float* Wih1 = (const float*)d_in[9];
    const float* Whh1 = (const float*)d_in[10];
    const float* bih1 = (const float*)d_in[11];
    const float* bhh1 = (const float*)d_in[12];
    const float* W2   = (const float*)d_in[13];
    const float* b2   = (const float*)d_in[14];
    const float* W3   = (const float*)d_in[15];
    const float* b3   = (const float*)d_in[16];

    float* ws   = (float*)d_ws;
    unsigned int* syncc = (unsigned int*)ws;  // [0]=cnt, [1]=gen (64-float slot)
    float* dist = ws + 64;                    // 2,097,152
    float* hist = dist + 2097152;             //   139,264
    float* X    = hist + 139264;              // 8,388,608 + 64 pad
    float* H0   = X + 8388672;                // 16,777,216
    float* S1   = H0 + 16777216;              //    32,768
    float* PB   = S1 + 32768;                 // 4 P buffers
    const size_t fixed = (size_t)(PB - ws);

    int TC = 16, tcs = 4;
    if ((fixed + 4ull * ((size_t)256 * 32 * 512 + 512)) * 4 <= ws_size) { TC = 32; tcs = 5; }
    const size_t pchunk = (size_t)256 * TC * 512 + 512;
    float* P0a = PB;
    float* P0b = PB + pchunk;
    float* P1a = PB + 2 * pchunk;
    float* P1b = PB + 3 * pchunk;

    hipMemsetAsync(syncc, 0, 64 * 4, stream);
    k_dist<<<dim3(64, 4), 256, 0, stream>>>(inp, akey, dist);
    k_softmax<<<256, 256, 0, stream>>>(dist);
    hipMemsetAsync(hist, 0, 139264 * 4, stream);
    k_hist<<<dim3(9, 4, 8), 256, 0, stream>>>(dist, aval, hist);
    k_xfeat<<<dim3(4, 256), 256, 0, stream>>>(inp, hist, W1, b1, X);

    PipeArgs pa;
    pa.X = X; pa.H0 = H0;
    pa.Wih0 = Wih0; pa.Wih1 = Wih1;
    pa.bih0 = bih0; pa.bhh0 = bhh0;
    pa.bih1 = bih1; pa.bhh1 = bhh1;
    pa.Whh0 = Whh0; pa.Whh1 = Whh1;
    pa.P0a = P0a; pa.P0b = P0b; pa.P1a = P1a; pa.P1b = P1b;
    pa.S1 = S1;
    pa.cnt = syncc; pa.gen = syncc + 1;
    pa.TC = TC; pa.tcs = tcs; pa.NC = 512 / TC;
    k_pipe<<<256, 512, 0, stream>>>(pa);

    k_tail<<<256, 64, 0, stream>>>(S1, W2, b2, W3, b3, (float*)d_out);
}

// Round 9
// 1310.634 us; speedup vs baseline: 3.3542x; 3.3542x over previous
//
#include <hip/hip_runtime.h>

typedef _Float16 h8 __attribute__((ext_vector_type(8)));
typedef float f32x4 __attribute__((ext_vector_type(4)));

__device__ __forceinline__ float fsigm(float x) {
    return __builtin_amdgcn_rcpf(1.0f + __expf(-x));
}
// tanh(x) = 1 - 2/(1+e^{2x}) : no abs/copysign, inf-safe (rcp(inf)=0).
__device__ __forceinline__ float ftanh(float x) {
    return 1.0f - 2.0f * __builtin_amdgcn_rcpf(1.0f + __expf(2.0f * x));
}
// LDS-only barrier: drains lgkmcnt, leaves global loads/stores in flight.
__device__ __forceinline__ void lds_barrier() {
    asm volatile("s_waitcnt lgkmcnt(0)\n\ts_barrier" ::: "memory");
}

// ---------------------------------------------------------------------------
// K1: dist[256][8192] = input[256][512] @ akey[8192][512]^T   (NT GEMM, fp32)
// ---------------------------------------------------------------------------
__global__ __launch_bounds__(256) void k_dist(const float* __restrict__ A,
                                              const float* __restrict__ Bm,
                                              float* __restrict__ C) {
    __shared__ float As[32][68];
    __shared__ float Bs[32][132];
    const int n0 = blockIdx.x * 128;
    const int m0 = blockIdx.y * 64;
    const int tid = threadIdx.x;
    const int tx = tid & 15;
    const int ty = tid >> 4;
    const int lm = tid >> 3;
    const int lk = (tid & 7) * 4;
    float acc[4][8];
#pragma unroll
    for (int i = 0; i < 4; ++i)
#pragma unroll
        for (int j = 0; j < 8; ++j) acc[i][j] = 0.0f;

    for (int kt = 0; kt < 512; kt += 32) {
        __syncthreads();
#pragma unroll
        for (int r = 0; r < 2; ++r) {
            int m = lm + 32 * r;
            float4 v = *(const float4*)&A[(size_t)(m0 + m) * 512 + kt + lk];
            As[lk + 0][m] = v.x; As[lk + 1][m] = v.y;
            As[lk + 2][m] = v.z; As[lk + 3][m] = v.w;
        }
#pragma unroll
        for (int r = 0; r < 4; ++r) {
            int n = lm + 32 * r;
            float4 v = *(const float4*)&Bm[(size_t)(n0 + n) * 512 + kt + lk];
            Bs[lk + 0][n] = v.x; Bs[lk + 1][n] = v.y;
            Bs[lk + 2][n] = v.z; Bs[lk + 3][n] = v.w;
        }
        __syncthreads();
#pragma unroll
        for (int k = 0; k < 32; ++k) {
            float4 a4 = *(const float4*)&As[k][ty * 4];
            float4 b0 = *(const float4*)&Bs[k][tx * 8];
            float4 b1 = *(const float4*)&Bs[k][tx * 8 + 4];
            float av[4] = {a4.x, a4.y, a4.z, a4.w};
            float bv[8] = {b0.x, b0.y, b0.z, b0.w, b1.x, b1.y, b1.z, b1.w};
#pragma unroll
            for (int i = 0; i < 4; ++i)
#pragma unroll
                for (int j = 0; j < 8; ++j)
                    acc[i][j] = fmaf(av[i], bv[j], acc[i][j]);
        }
    }
#pragma unroll
    for (int i = 0; i < 4; ++i) {
        size_t row = (size_t)(m0 + ty * 4 + i) * 8192 + n0 + tx * 8;
        *(float4*)&C[row]     = make_float4(acc[i][0], acc[i][1], acc[i][2], acc[i][3]);
        *(float4*)&C[row + 4] = make_float4(acc[i][4], acc[i][5], acc[i][6], acc[i][7]);
    }
}

// ---------------------------------------------------------------------------
// K2: per-row argmax (first index on ties) -> set 0 -> softmax, in place
// ---------------------------------------------------------------------------
__global__ __launch_bounds__(256) void k_softmax(float* __restrict__ D) {
    __shared__ float row[8192];
    __shared__ float rv[256];
    __shared__ int   ri[256];
    const int b = blockIdx.x, tid = threadIdx.x;
    float* dr = D + (size_t)b * 8192;
    for (int i = tid; i < 2048; i += 256)
        *(float4*)&row[i * 4] = *(const float4*)&dr[i * 4];
    __syncthreads();

    float bv = -INFINITY; int bi = 0x7fffffff;
    for (int i = tid; i < 8192; i += 256) {
        float v = row[i];
        if (v > bv || (v == bv && i < bi)) { bv = v; bi = i; }
    }
    rv[tid] = bv; ri[tid] = bi;
    __syncthreads();
    for (int s = 128; s > 0; s >>= 1) {
        if (tid < s) {
            float ov = rv[tid + s]; int oi = ri[tid + s];
            if (ov > rv[tid] || (ov == rv[tid] && oi < ri[tid])) { rv[tid] = ov; ri[tid] = oi; }
        }
        __syncthreads();
    }
    if (tid == 0) row[ri[0]] = 0.0f;
    __syncthreads();

    float m = -INFINITY;
    for (int i = tid; i < 8192; i += 256) m = fmaxf(m, row[i]);
    rv[tid] = m;
    __syncthreads();
    for (int s = 128; s > 0; s >>= 1) {
        if (tid < s) rv[tid] = fmaxf(rv[tid], rv[tid + s]);
        __syncthreads();
    }
    const float M = rv[0];
    __syncthreads();

    float ssum = 0.0f;
    for (int i = tid; i < 8192; i += 256) {
        float e = __expf(row[i] - M);
        row[i] = e;
        ssum += e;
    }
    rv[tid] = ssum;
    __syncthreads();
    for (int s = 128; s > 0; s >>= 1) {
        if (tid < s) rv[tid] += rv[tid + s];
        __syncthreads();
    }
    const float inv = 1.0f / rv[0];
    for (int i = tid; i < 2048; i += 256) {
        float4 v = *(float4*)&row[i * 4];
        v.x *= inv; v.y *= inv; v.z *= inv; v.w *= inv;
        *(float4*)&dr[i * 4] = v;
    }
}

// ---------------------------------------------------------------------------
// K3: hist[256][544] += a[256][8192] @ aval[8192][544]  (NN GEMM, split-K=8)
// ---------------------------------------------------------------------------
__global__ __launch_bounds__(256) void k_hist(const float* __restrict__ A,
                                              const float* __restrict__ Bm,
                                              float* __restrict__ C) {
    __shared__ float As[32][68];
    __shared__ float Bs[32][68];
    const int n0 = blockIdx.x * 64;
    const int m0 = blockIdx.y * 64;
    const int kz = blockIdx.z;
    const int tid = threadIdx.x;
    const int tx = tid & 15, ty = tid >> 4;
    const int lr = tid >> 3;
    const int lq = (tid & 7) * 4;
    float acc[4][4];
#pragma unroll
    for (int i = 0; i < 4; ++i)
#pragma unroll
        for (int j = 0; j < 4; ++j) acc[i][j] = 0.0f;

    const int k_lo = kz * 1024, k_hi = k_lo + 1024;
    for (int kt = k_lo; kt < k_hi; kt += 32) {
        __syncthreads();
#pragma unroll
        for (int r = 0; r < 2; ++r) {
            int m = lr + 32 * r;
            float4 v = *(const float4*)&A[(size_t)(m0 + m) * 8192 + kt + lq];
            As[lq + 0][m] = v.x; As[lq + 1][m] = v.y;
            As[lq + 2][m] = v.z; As[lq + 3][m] = v.w;
        }
#pragma unroll
        for (int r = 0; r < 2; ++r) {
            int kk = (tid >> 4) + 16 * r;
            int nq = (tid & 15) * 4;
            float4 v = make_float4(0.f, 0.f, 0.f, 0.f);
            if (n0 + nq < 544)
                v = *(const float4*)&Bm[(size_t)(kt + kk) * 544 + n0 + nq];
            *(float4*)&Bs[kk][nq] = v;
        }
        __syncthreads();
#pragma unroll
        for (int k = 0; k < 32; ++k) {
            float4 a4 = *(const float4*)&As[k][ty * 4];
            float4 b4 = *(const float4*)&Bs[k][tx * 4];
            float av[4] = {a4.x, a4.y, a4.z, a4.w};
            float bv[4] = {b4.x, b4.y, b4.z, b4.w};
#pragma unroll
            for (int i = 0; i < 4; ++i)
#pragma unroll
                for (int j = 0; j < 4; ++j)
                    acc[i][j] = fmaf(av[i], bv[j], acc[i][j]);
        }
    }
#pragma unroll
    for (int i = 0; i < 4; ++i)
#pragma unroll
        for (int j = 0; j < 4; ++j) {
            int n = n0 + tx * 4 + j;
            if (n < 544)
                atomicAdd(&C[(size_t)(m0 + ty * 4 + i) * 544 + n], acc[i][j]);
        }
}

// ---------------------------------------------------------------------------
// K4: x[b][t][o] = tanh(b1[o] + W1[o][0]*input[b][t] + sum_j W1[o][1+j]*hist[b][t+j])
// ---------------------------------------------------------------------------
__global__ __launch_bounds__(256) void k_xfeat(const float* __restrict__ inp,
                                               const float* __restrict__ hist,
                                               const float* __restrict__ W1,
                                               const float* __restrict__ b1,
                                               float* __restrict__ X) {
    __shared__ float w[33 * 64];
    __shared__ float bl[64];
    __shared__ float il[128];
    __shared__ float hl[160];
    const int t0 = blockIdx.x * 128;
    const int b  = blockIdx.y;
    const int tid = threadIdx.x;
    for (int idx = tid; idx < 2112; idx += 256) {
        int o = idx / 33, k = idx % 33;
        w[k * 64 + o] = W1[idx];
    }
    if (tid < 64) bl[tid] = b1[tid];
    if (tid < 128) il[tid] = inp[(size_t)b * 512 + t0 + tid];
    for (int i = tid; i < 159; i += 256) hl[i] = hist[(size_t)b * 544 + t0 + i];
    __syncthreads();
    const int o = tid & 63, tq = tid >> 6;
    for (int it = 0; it < 32; ++it) {
        int tl = it * 4 + tq;
        float acc = fmaf(il[tl], w[o], bl[o]);
#pragma unroll
        for (int j = 0; j < 32; ++j)
            acc = fmaf(hl[tl + j], w[(1 + j) * 64 + o], acc);
        X[(size_t)(b * 512 + t0 + tl) * 64 + o] = ftanh(acc);
    }
}

// ---------------------------------------------------------------------------
// Pre-gate GEMM body, 512 threads, tile 64(m) x 128(n) x 32(k).
// ---------------------------------------------------------------------------
template <int K>
__device__ __forceinline__ void pregemm_body(const float* __restrict__ A,
                                             const float* __restrict__ Bw,
                                             const float* __restrict__ bih,
                                             const float* __restrict__ bhh,
                                             float* __restrict__ C,
                                             int t0, int tcs, int gb, float* sm) {
    float* As = sm;             // [32][68]
    float* Bs = sm + 32 * 68;   // [32][132]
    const int n0 = (gb & 3) * 128;
    const int m0 = (gb >> 2) * 64;
    const int tid = threadIdx.x;
    const int tx = tid & 31;
    const int ty = tid >> 5;
    const int lm = tid >> 3;
    const int lk = (tid & 7) * 4;
    const int ln = tid >> 2;
    const int lkb = (tid & 3) * 8;
    const int tcm = (1 << tcs) - 1;
    float acc[4][4];
#pragma unroll
    for (int i = 0; i < 4; ++i)
#pragma unroll
        for (int j = 0; j < 4; ++j) acc[i][j] = 0.0f;

    for (int kt = 0; kt < K; kt += 32) {
        __syncthreads();
        {
            int m = m0 + lm;
            size_t arow = (size_t)(m >> tcs) * 512 + t0 + (m & tcm);
            float4 v = *(const float4*)&A[arow * K + kt + lk];
            As[(lk + 0) * 68 + lm] = v.x; As[(lk + 1) * 68 + lm] = v.y;
            As[(lk + 2) * 68 + lm] = v.z; As[(lk + 3) * 68 + lm] = v.w;
        }
        {
            const float* bp = &Bw[(size_t)(n0 + ln) * K + kt + lkb];
            float4 v0 = *(const float4*)bp;
            float4 v1 = *(const float4*)(bp + 4);
            Bs[(lkb + 0) * 132 + ln] = v0.x; Bs[(lkb + 1) * 132 + ln] = v0.y;
            Bs[(lkb + 2) * 132 + ln] = v0.z; Bs[(lkb + 3) * 132 + ln] = v0.w;
            Bs[(lkb + 4) * 132 + ln] = v1.x; Bs[(lkb + 5) * 132 + ln] = v1.y;
            Bs[(lkb + 6) * 132 + ln] = v1.z; Bs[(lkb + 7) * 132 + ln] = v1.w;
        }
        __syncthreads();
#pragma unroll
        for (int k = 0; k < 32; ++k) {
            float4 a4 = *(const float4*)&As[k * 68 + ty * 4];
            float4 b4 = *(const float4*)&Bs[k * 132 + tx * 4];
            float av[4] = {a4.x, a4.y, a4.z, a4.w};
            float bv[4] = {b4.x, b4.y, b4.z, b4.w};
#pragma unroll
            for (int i = 0; i < 4; ++i)
#pragma unroll
                for (int j = 0; j < 4; ++j)
                    acc[i][j] = fmaf(av[i], bv[j], acc[i][j]);
        }
    }
    float bb[4];
#pragma unroll
    for (int j = 0; j < 4; ++j) {
        int n = n0 + tx * 4 + j;
        bb[j] = bih[n] + bhh[n];
    }
#pragma unroll
    for (int i = 0; i < 4; ++i) {
        size_t row = (size_t)(m0 + ty * 4 + i) * 512 + n0 + tx * 4;
        *(float4*)&C[row] = make_float4(acc[i][0] + bb[0], acc[i][1] + bb[1],
                                        acc[i][2] + bb[2], acc[i][3] + bb[3]);
    }
}

// ---------------------------------------------------------------------------
// MFMA LSTM recurrence over one t-chunk (lane-local gates, double-buffered
// fp16 hi/lo h planes, one lgkm-only barrier/step).
// ---------------------------------------------------------------------------
__device__ __forceinline__ void rec_body(const float* __restrict__ P,
                                         const float* __restrict__ Whh,
                                         float* __restrict__ S,
                                         float* __restrict__ Hout,
                                         int t0, int TC, int blk, float* sm) {
    unsigned int* hpb = (unsigned int*)sm;   // [buf][pl][16][72] dwords
#define HPROW(buf, pl, m) ((_Float16*)(hpb + ((((buf)*2 + (pl))*16 + (m)) * 72)))
    const int b0   = blk * 16;
    const int tid  = threadIdx.x;
    const int lane = tid & 63;
    const int wv   = tid >> 6;
    const int quad = lane >> 4;
    const int l15  = lane & 15;
    const int hu   = wv * 16 + l15;

    h8 bh[4][4], bl[4][4];
#pragma unroll
    for (int g = 0; g < 4; ++g) {
        int n = g * 128 + hu;
#pragma unroll
        for (int q = 0; q < 4; ++q) {
            int kb = q * 32 + quad * 8;
            const float* wp = &Whh[(size_t)n * 128 + kb];
            float4 w0 = *(const float4*)wp;
            float4 w1 = *(const float4*)(wp + 4);
            float we[8] = {w0.x, w0.y, w0.z, w0.w, w1.x, w1.y, w1.z, w1.w};
#pragma unroll
            for (int j = 0; j < 8; ++j) {
                _Float16 hi = (_Float16)we[j];
                bh[g][q][j] = hi;
                bl[g][q][j] = (_Float16)(we[j] - (float)hi);
            }
        }
    }

    float c[4];
#pragma unroll
    for (int r = 0; r < 4; ++r) {
        int m = quad * 4 + r;
        float h = S[(size_t)(b0 + m) * 128 + hu];
        c[r] = S[32768 + (size_t)(b0 + m) * 128 + hu];
        _Float16 hh = (_Float16)h;
        HPROW(0, 0, m)[hu] = hh;
        HPROW(0, 1, m)[hu] = (_Float16)(h - (float)hh);
    }
    lds_barrier();

    int off[4][4];
#pragma unroll
    for (int g = 0; g < 4; ++g)
#pragma unroll
        for (int r = 0; r < 4; ++r)
            off[g][r] = (b0 + quad * 4 + r) * TC * 512 + g * 128 + hu;

    float pc[4][4];
#pragma unroll
    for (int g = 0; g < 4; ++g)
#pragma unroll
        for (int r = 0; r < 4; ++r)
            pc[g][r] = P[off[g][r]];

    const bool wr = (Hout != nullptr);
    const float* Pn = P + 512;
    float* Ho = wr ? (Hout + (size_t)t0 * 128) : nullptr;

    for (int tl = 0; tl < TC; ++tl) {
        float pn[4][4];
#pragma unroll
        for (int g = 0; g < 4; ++g)
#pragma unroll
            for (int r = 0; r < 4; ++r)
                pn[g][r] = Pn[off[g][r]];

        const int rb = tl & 1;
        h8 ah[4], al[4];
#pragma unroll
        for (int q = 0; q < 4; ++q) {
            int hoff = 32 * q + 8 * quad;
            ah[q] = *(const h8*)&HPROW(rb, 0, l15)[hoff];
            al[q] = *(const h8*)&HPROW(rb, 1, l15)[hoff];
        }

        f32x4 acc[4];
#pragma unroll
        for (int g = 0; g < 4; ++g) {
            acc[g][0] = pc[g][0]; acc[g][1] = pc[g][1];
            acc[g][2] = pc[g][2]; acc[g][3] = pc[g][3];
        }
#pragma unroll
        for (int q = 0; q < 4; ++q) {
#pragma unroll
            for (int g = 0; g < 4; ++g) {
                acc[g] = __builtin_amdgcn_mfma_f32_16x16x32_f16(ah[q], bh[g][q], acc[g], 0, 0, 0);
                acc[g] = __builtin_amdgcn_mfma_f32_16x16x32_f16(al[q], bh[g][q], acc[g], 0, 0, 0);
                acc[g] = __builtin_amdgcn_mfma_f32_16x16x32_f16(ah[q], bl[g][q], acc[g], 0, 0, 0);
            }
        }

        const int wb = (tl + 1) & 1;
#pragma unroll
        for (int r = 0; r < 4; ++r) {
            int m = quad * 4 + r;
            float iv = fsigm(acc[0][r]);
            float fv = fsigm(acc[1][r]);
            float gv = ftanh(acc[2][r]);
            float ov = fsigm(acc[3][r]);
            c[r] = fv * c[r] + iv * gv;
            float h = ov * ftanh(c[r]);
            _Float16 hh = (_Float16)h;
            HPROW(wb, 0, m)[hu] = hh;
            HPROW(wb, 1, m)[hu] = (_Float16)(h - (float)hh);
            if (wr) Ho[((size_t)(b0 + m) * 512 + tl) * 128 + hu] = h;
            if (tl == TC - 1) {
                S[(size_t)(b0 + m) * 128 + hu] = h;
                S[32768 + (size_t)(b0 + m) * 128 + hu] = c[r];
            }
        }
        lds_barrier();

        Pn += 512;
#pragma unroll
        for (int g = 0; g < 4; ++g)
#pragma unroll
            for (int r = 0; r < 4; ++r)
                pc[g][r] = pn[g][r];
    }
#undef HPROW
}

// ---------------------------------------------------------------------------
// K5: fused pipeline stage (multi-launch, NOT persistent). Blocks 0-15: rec0
// chunk k. 16-31: rec1 chunk k-2. Rest: pre-gate GEMMs (pre0 k+1, pre1 k-1).
// 80 KB LDS declared -> exactly 1 block/CU, so rec blocks own their 32 CUs
// exclusively (zero GEMM interference); GEMM backfills the other 224 CUs.
// Launch boundaries provide ordering; P0/P1 double-buffered.
// ---------------------------------------------------------------------------
__global__ __launch_bounds__(512, 1) void k_fused(
        const float* __restrict__ X,    const float* __restrict__ H0,
        const float* __restrict__ Wih0, const float* __restrict__ Wih1,
        const float* __restrict__ bih0, const float* __restrict__ bhh0,
        const float* __restrict__ bih1, const float* __restrict__ bhh1,
        const float* __restrict__ Whh0, const float* __restrict__ Whh1,
        const float* __restrict__ P0r, float* __restrict__ P0w,
        const float* __restrict__ P1r, float* __restrict__ P1w,
        float* __restrict__ S0, float* __restrict__ S1, float* __restrict__ H0out,
        int tr0, int tr1, int tp0, int tp1,
        int v_rec0, int v_rec1, int v_pre0, int v_pre1,
        int TC, int tcs) {
    __shared__ float smem[20480];   // 80 KB -> 1 block/CU (CU isolation)
    const int bid = blockIdx.x;
    if (bid < 16) {
        if (v_rec0) rec_body(P0r, Whh0, S0, H0out, tr0, TC, bid, smem);
        return;
    }
    if (bid < 32) {
        if (v_rec1) rec_body(P1r, Whh1, S1, nullptr, tr1, TC, bid - 16, smem);
        return;
    }
    int gb = bid - 32;
    const int npre = 16 * TC;
    if (gb < npre) {
        if (v_pre0) pregemm_body<64>(X, Wih0, bih0, bhh0, P0w, tp0, tcs, gb, smem);
        return;
    }
    gb -= npre;
    if (v_pre1) pregemm_body<128>(H0, Wih1, bih1, bhh1, P1w, tp1, tcs, gb, smem);
}

// ---------------------------------------------------------------------------
// K6: tail head: out = tanh(tanh(h1_last) @ W2^T + b2) @ W3^T + b3
// ---------------------------------------------------------------------------
__global__ __launch_bounds__(64) void k_tail(const float* __restrict__ Hs,
                                             const float* __restrict__ W2,
                                             const float* __restrict__ b2,
                                             const float* __restrict__ W3,
                                             const float* __restrict__ b3,
                                             float* __restrict__ out) {
    __shared__ float last[128], l2s[64];
    const int b = blockIdx.x, tid = threadIdx.x;
    last[tid]      = ftanh(Hs[(size_t)b * 128 + tid]);
    last[tid + 64] = ftanh(Hs[(size_t)b * 128 + 64 + tid]);
    __syncthreads();
    float acc = b2[tid];
#pragma unroll 4
    for (int j = 0; j < 128; ++j) acc = fmaf(W2[(size_t)tid * 128 + j], last[j], acc);
    l2s[tid] = ftanh(acc);
    __syncthreads();
    if (tid < 32) {
        float a2 = b3[tid];
#pragma unroll 4
        for (int o = 0; o < 64; ++o) a2 = fmaf(W3[(size_t)tid * 64 + o], l2s[o], a2);
        out[(size_t)b * 32 + tid] = a2;
    }
}

// ---------------------------------------------------------------------------
extern "C" void kernel_launch(void* const* d_in, const int* in_sizes, int n_in,
                              void* d_out, int out_size, void* d_ws, size_t ws_size,
                              hipStream_t stream) {
    (void)in_sizes; (void)n_in; (void)out_size;
    const float* inp  = (const float*)d_in[0];
    const float* akey = (const float*)d_in[1];
    const float* aval = (const float*)d_in[2];
    const float* W1   = (const float*)d_in[3];
    const float* b1   = (const float*)d_in[4];
    const float* Wih0 = (const float*)d_in[5];
    const float* Whh0 = (const float*)d_in[6];
    const float* bih0 = (const float*)d_in[7];
    const float* bhh0 = (const float*)d_in[8];
    const float* Wih1 = (const float*)d_in[9];
    const float* Whh1 = (const float*)d_in[10];
    const float* bih1 = (const float*)d_in[11];
    const float* bhh1 = (const float*)d_in[12];
    const float* W2   = (const float*)d_in[13];
    const float* b2   = (const float*)d_in[14];
    const float* W3   = (const float*)d_in[15];
    const float* b3   = (const float*)d_in[16];

    float* ws   = (float*)d_ws;
    float* dist = ws;                       // 2,097,152
    float* hist = dist + 2097152;           //   139,264
    float* X    = hist + 139264;            // 8,388,608 + 64 pad
    float* S0   = X + 8388672;              //    65,536 (h then c)
    float* S1   = S0 + 65536;               //    65,536
    float* H0   = S1 + 65536;               // 16,777,216  (h0, [b][512][128])
    float* PB   = H0 + 16777216;            // 4 P buffers
    const size_t fixed = (size_t)(PB - ws);

    // 4 P buffers of 256*TC*512 + 512 floats (P0 x2, P1 x2 ping-pong)
    int TC = 16, tcs = 4;
    if ((fixed + 4ull * ((size_t)256 * 32 * 512 + 512)) * 4 <= ws_size) { TC = 32; tcs = 5; }
    const size_t pchunk = (size_t)256 * TC * 512 + 512;
    float* P0b[2] = {PB, PB + pchunk};
    float* P1b[2] = {PB + 2 * pchunk, PB + 3 * pchunk};

    k_dist<<<dim3(64, 4), 256, 0, stream>>>(inp, akey, dist);
    k_softmax<<<256, 256, 0, stream>>>(dist);
    hipMemsetAsync(hist, 0, 139264 * 4, stream);
    k_hist<<<dim3(9, 4, 8), 256, 0, stream>>>(dist, aval, hist);
    k_xfeat<<<dim3(4, 256), 256, 0, stream>>>(inp, hist, W1, b1, X);
    hipMemsetAsync(S0, 0, (size_t)2 * 65536 * 4, stream);  // S0+S1 contiguous

    const int NC = 512 / TC;
    const int nblocks = 32 + 32 * TC;   // 32 rec + 16*TC pre0 + 16*TC pre1
    for (int k = -1; k <= NC + 1; ++k) {
        int v_rec0 = (k >= 0 && k < NC);
        int v_rec1 = (k >= 2 && k < NC + 2);
        int v_pre0 = (k + 1 >= 0 && k + 1 < NC);
        int v_pre1 = (k - 1 >= 0 && k - 1 < NC);
        if (!(v_rec0 | v_rec1 | v_pre0 | v_pre1)) continue;
        const float* P0r = P0b[k & 1];
        float*       P0w = P0b[(k + 1) & 1];
        const float* P1r = P1b[k & 1];
        float*       P1w = P1b[(k + 1) & 1];
        k_fused<<<nblocks, 512, 0, stream>>>(
            X, H0, Wih0, Wih1, bih0, bhh0, bih1, bhh1, Whh0, Whh1,
            P0r, P0w, P1r, P1w, S0, S1, H0,
            k * TC, (k - 2) * TC, (k + 1) * TC, (k - 1) * TC,
            v_rec0, v_rec1, v_pre0, v_pre1, TC, tcs);
    }
    k_tail<<<256, 64, 0, stream>>>(S1, W2, b2, W3, b3, (float*)d_out);
}

// Round 10
// 1309.631 us; speedup vs baseline: 3.3568x; 1.0008x over previous
//
#include <hip/hip_runtime.h>

typedef _Float16 h8 __attribute__((ext_vector_type(8)));
typedef _Float16 h4 __attribute__((ext_vector_type(4)));
typedef float f32x4 __attribute__((ext_vector_type(4)));

__device__ __forceinline__ float fsigm(float x) {
    return __builtin_amdgcn_rcpf(1.0f + __expf(-x));
}
// tanh(x) = 1 - 2/(1+e^{2x}) : no abs/copysign, inf-safe (rcp(inf)=0).
__device__ __forceinline__ float ftanh(float x) {
    return 1.0f - 2.0f * __builtin_amdgcn_rcpf(1.0f + __expf(2.0f * x));
}
// LDS-only barrier: drains lgkmcnt, leaves global loads/stores in flight.
__device__ __forceinline__ void lds_barrier() {
    asm volatile("s_waitcnt lgkmcnt(0)\n\ts_barrier" ::: "memory");
}

// ---------------------------------------------------------------------------
// K1: dist[256][8192] = input[256][512] @ akey[8192][512]^T
// MFMA f16 hi/lo (3 products). Tile 64m x 128n, 256 thr (4 waves), K-step 32.
// Fragment layout identical to the (verified) recurrence kernel.
// ---------------------------------------------------------------------------
__global__ __launch_bounds__(256) void k_distM(const float* __restrict__ A,
                                               const float* __restrict__ Bm,
                                               float* __restrict__ C) {
    __shared__ _Float16 Ah[64][40], Al[64][40];     // [m][k], pad 40 (80B rows)
    __shared__ _Float16 Bh[128][40], Bl[128][40];   // [n][k]
    const int n0 = blockIdx.x * 128;
    const int m0 = blockIdx.y * 64;
    const int tid = threadIdx.x;
    const int lane = tid & 63, wv = tid >> 6;
    const int quad = lane >> 4, l15 = lane & 15;
    f32x4 acc[8];
#pragma unroll
    for (int i = 0; i < 8; ++i) acc[i] = (f32x4){0.f, 0.f, 0.f, 0.f};

    for (int kt = 0; kt < 512; kt += 32) {
        __syncthreads();
#pragma unroll
        for (int r = 0; r < 2; ++r) {           // A: 64x32 = 512 float4
            int idx = tid + 256 * r;
            int m = idx >> 3, kq = (idx & 7) * 4;
            float4 v = *(const float4*)&A[(size_t)(m0 + m) * 512 + kt + kq];
            float e[4] = {v.x, v.y, v.z, v.w};
            h4 hi, lo;
#pragma unroll
            for (int j = 0; j < 4; ++j) {
                _Float16 h = (_Float16)e[j];
                hi[j] = h; lo[j] = (_Float16)(e[j] - (float)h);
            }
            *(h4*)&Ah[m][kq] = hi;
            *(h4*)&Al[m][kq] = lo;
        }
#pragma unroll
        for (int r = 0; r < 4; ++r) {           // B: 128x32 = 1024 float4
            int idx = tid + 256 * r;
            int n = idx >> 3, kq = (idx & 7) * 4;
            float4 v = *(const float4*)&Bm[(size_t)(n0 + n) * 512 + kt + kq];
            float e[4] = {v.x, v.y, v.z, v.w};
            h4 hi, lo;
#pragma unroll
            for (int j = 0; j < 4; ++j) {
                _Float16 h = (_Float16)e[j];
                hi[j] = h; lo[j] = (_Float16)(e[j] - (float)h);
            }
            *(h4*)&Bh[n][kq] = hi;
            *(h4*)&Bl[n][kq] = lo;
        }
        __syncthreads();
        h8 ah = *(const h8*)&Ah[wv * 16 + l15][quad * 8];
        h8 al = *(const h8*)&Al[wv * 16 + l15][quad * 8];
#pragma unroll
        for (int nt = 0; nt < 8; ++nt) {
            h8 bhf = *(const h8*)&Bh[nt * 16 + l15][quad * 8];
            h8 blf = *(const h8*)&Bl[nt * 16 + l15][quad * 8];
            acc[nt] = __builtin_amdgcn_mfma_f32_16x16x32_f16(ah, bhf, acc[nt], 0, 0, 0);
            acc[nt] = __builtin_amdgcn_mfma_f32_16x16x32_f16(al, bhf, acc[nt], 0, 0, 0);
            acc[nt] = __builtin_amdgcn_mfma_f32_16x16x32_f16(ah, blf, acc[nt], 0, 0, 0);
        }
    }
#pragma unroll
    for (int nt = 0; nt < 8; ++nt)
#pragma unroll
        for (int r = 0; r < 4; ++r)
            C[(size_t)(m0 + wv * 16 + quad * 4 + r) * 8192 + n0 + nt * 16 + l15] = acc[nt][r];
}

// ---------------------------------------------------------------------------
// K2: per-row argmax (first index on ties) -> set 0 -> softmax, in place
// ---------------------------------------------------------------------------
__global__ __launch_bounds__(256) void k_softmax(float* __restrict__ D) {
    __shared__ float row[8192];
    __shared__ float rv[256];
    __shared__ int   ri[256];
    const int b = blockIdx.x, tid = threadIdx.x;
    float* dr = D + (size_t)b * 8192;
    for (int i = tid; i < 2048; i += 256)
        *(float4*)&row[i * 4] = *(const float4*)&dr[i * 4];
    __syncthreads();

    float bv = -INFINITY; int bi = 0x7fffffff;
    for (int i = tid; i < 8192; i += 256) {
        float v = row[i];
        if (v > bv || (v == bv && i < bi)) { bv = v; bi = i; }
    }
    rv[tid] = bv; ri[tid] = bi;
    __syncthreads();
    for (int s = 128; s > 0; s >>= 1) {
        if (tid < s) {
            float ov = rv[tid + s]; int oi = ri[tid + s];
            if (ov > rv[tid] || (ov == rv[tid] && oi < ri[tid])) { rv[tid] = ov; ri[tid] = oi; }
        }
        __syncthreads();
    }
    if (tid == 0) row[ri[0]] = 0.0f;
    __syncthreads();

    float m = -INFINITY;
    for (int i = tid; i < 8192; i += 256) m = fmaxf(m, row[i]);
    rv[tid] = m;
    __syncthreads();
    for (int s = 128; s > 0; s >>= 1) {
        if (tid < s) rv[tid] = fmaxf(rv[tid], rv[tid + s]);
        __syncthreads();
    }
    const float M = rv[0];
    __syncthreads();

    float ssum = 0.0f;
    for (int i = tid; i < 8192; i += 256) {
        float e = __expf(row[i] - M);
        row[i] = e;
        ssum += e;
    }
    rv[tid] = ssum;
    __syncthreads();
    for (int s = 128; s > 0; s >>= 1) {
        if (tid < s) rv[tid] += rv[tid + s];
        __syncthreads();
    }
    const float inv = 1.0f / rv[0];
    for (int i = tid; i < 2048; i += 256) {
        float4 v = *(float4*)&row[i * 4];
        v.x *= inv; v.y *= inv; v.z *= inv; v.w *= inv;
        *(float4*)&dr[i * 4] = v;
    }
}

// ---------------------------------------------------------------------------
// K3: hist[256][544] += a[256][8192] @ aval[8192][544]
// MFMA f16 hi/lo, split-K=8, tile 64m x 64n, aval transposed during staging.
// ---------------------------------------------------------------------------
__global__ __launch_bounds__(256) void k_histM(const float* __restrict__ A,
                                               const float* __restrict__ Bm,
                                               float* __restrict__ C) {
    __shared__ _Float16 Ah[64][40], Al[64][40];   // [m][k]
    __shared__ _Float16 Bh[64][40], Bl[64][40];   // [n][k] (transposed aval)
    const int n0 = blockIdx.x * 64;
    const int m0 = blockIdx.y * 64;
    const int kz = blockIdx.z;
    const int tid = threadIdx.x;
    const int lane = tid & 63, wv = tid >> 6;
    const int quad = lane >> 4, l15 = lane & 15;
    f32x4 acc[4];
#pragma unroll
    for (int i = 0; i < 4; ++i) acc[i] = (f32x4){0.f, 0.f, 0.f, 0.f};

    const int k_lo = kz * 1024, k_hi = k_lo + 1024;
    for (int kt = k_lo; kt < k_hi; kt += 32) {
        __syncthreads();
#pragma unroll
        for (int r = 0; r < 2; ++r) {           // A: 64x32 = 512 float4
            int idx = tid + 256 * r;
            int m = idx >> 3, kq = (idx & 7) * 4;
            float4 v = *(const float4*)&A[(size_t)(m0 + m) * 8192 + kt + kq];
            float e[4] = {v.x, v.y, v.z, v.w};
            h4 hi, lo;
#pragma unroll
            for (int j = 0; j < 4; ++j) {
                _Float16 h = (_Float16)e[j];
                hi[j] = h; lo[j] = (_Float16)(e[j] - (float)h);
            }
            *(h4*)&Ah[m][kq] = hi;
            *(h4*)&Al[m][kq] = lo;
        }
#pragma unroll
        for (int r = 0; r < 2; ++r) {           // B: aval[32k][64n] -> [n][k]
            int idx = tid + 256 * r;
            int kk = idx >> 4;                  // 0..31
            int nq = (idx & 15) * 4;            // 0..60
            float4 v = make_float4(0.f, 0.f, 0.f, 0.f);
            if (n0 + nq < 544)
                v = *(const float4*)&Bm[(size_t)(kt + kk) * 544 + n0 + nq];
            float e[4] = {v.x, v.y, v.z, v.w};
#pragma unroll
            for (int j = 0; j < 4; ++j) {
                _Float16 h = (_Float16)e[j];
                Bh[nq + j][kk] = h;
                Bl[nq + j][kk] = (_Float16)(e[j] - (float)h);
            }
        }
        __syncthreads();
        h8 ah = *(const h8*)&Ah[wv * 16 + l15][quad * 8];
        h8 al = *(const h8*)&Al[wv * 16 + l15][quad * 8];
#pragma unroll
        for (int nt = 0; nt < 4; ++nt) {
            h8 bhf = *(const h8*)&Bh[nt * 16 + l15][quad * 8];
            h8 blf = *(const h8*)&Bl[nt * 16 + l15][quad * 8];
            acc[nt] = __builtin_amdgcn_mfma_f32_16x16x32_f16(ah, bhf, acc[nt], 0, 0, 0);
            acc[nt] = __builtin_amdgcn_mfma_f32_16x16x32_f16(al, bhf, acc[nt], 0, 0, 0);
            acc[nt] = __builtin_amdgcn_mfma_f32_16x16x32_f16(ah, blf, acc[nt], 0, 0, 0);
        }
    }
#pragma unroll
    for (int nt = 0; nt < 4; ++nt)
#pragma unroll
        for (int r = 0; r < 4; ++r) {
            int n = n0 + nt * 16 + l15;
            if (n < 544)
                atomicAdd(&C[(size_t)(m0 + wv * 16 + quad * 4 + r) * 544 + n], acc[nt][r]);
        }
}

// ---------------------------------------------------------------------------
// K4: x[b][t][o] = tanh(b1[o] + W1[o][0]*input[b][t] + sum_j W1[o][1+j]*hist[b][t+j])
// ---------------------------------------------------------------------------
__global__ __launch_bounds__(256) void k_xfeat(const float* __restrict__ inp,
                                               const float* __restrict__ hist,
                                               const float* __restrict__ W1,
                                               const float* __restrict__ b1,
                                               float* __restrict__ X) {
    __shared__ float w[33 * 64];
    __shared__ float bl[64];
    __shared__ float il[128];
    __shared__ float hl[160];
    const int t0 = blockIdx.x * 128;
    const int b  = blockIdx.y;
    const int tid = threadIdx.x;
    for (int idx = tid; idx < 2112; idx += 256) {
        int o = idx / 33, k = idx % 33;
        w[k * 64 + o] = W1[idx];
    }
    if (tid < 64) bl[tid] = b1[tid];
    if (tid < 128) il[tid] = inp[(size_t)b * 512 + t0 + tid];
    for (int i = tid; i < 159; i += 256) hl[i] = hist[(size_t)b * 544 + t0 + i];
    __syncthreads();
    const int o = tid & 63, tq = tid >> 6;
    for (int it = 0; it < 32; ++it) {
        int tl = it * 4 + tq;
        float acc = fmaf(il[tl], w[o], bl[o]);
#pragma unroll
        for (int j = 0; j < 32; ++j)
            acc = fmaf(hl[tl + j], w[(1 + j) * 64 + o], acc);
        X[(size_t)(b * 512 + t0 + tl) * 64 + o] = ftanh(acc);
    }
}

// ---------------------------------------------------------------------------
// Pre-gate GEMM body, 512 threads, tile 64(m) x 128(n) x 32(k).
// ---------------------------------------------------------------------------
template <int K>
__device__ __forceinline__ void pregemm_body(const float* __restrict__ A,
                                             const float* __restrict__ Bw,
                                             const float* __restrict__ bih,
                                             const float* __restrict__ bhh,
                                             float* __restrict__ C,
                                             int t0, int tcs, int gb, float* sm) {
    float* As = sm;             // [32][68]
    float* Bs = sm + 32 * 68;   // [32][132]
    const int n0 = (gb & 3) * 128;
    const int m0 = (gb >> 2) * 64;
    const int tid = threadIdx.x;
    const int tx = tid & 31;
    const int ty = tid >> 5;
    const int lm = tid >> 3;
    const int lk = (tid & 7) * 4;
    const int ln = tid >> 2;
    const int lkb = (tid & 3) * 8;
    const int tcm = (1 << tcs) - 1;
    float acc[4][4];
#pragma unroll
    for (int i = 0; i < 4; ++i)
#pragma unroll
        for (int j = 0; j < 4; ++j) acc[i][j] = 0.0f;

    for (int kt = 0; kt < K; kt += 32) {
        __syncthreads();
        {
            int m = m0 + lm;
            size_t arow = (size_t)(m >> tcs) * 512 + t0 + (m & tcm);
            float4 v = *(const float4*)&A[arow * K + kt + lk];
            As[(lk + 0) * 68 + lm] = v.x; As[(lk + 1) * 68 + lm] = v.y;
            As[(lk + 2) * 68 + lm] = v.z; As[(lk + 3) * 68 + lm] = v.w;
        }
        {
            const float* bp = &Bw[(size_t)(n0 + ln) * K + kt + lkb];
            float4 v0 = *(const float4*)bp;
            float4 v1 = *(const float4*)(bp + 4);
            Bs[(lkb + 0) * 132 + ln] = v0.x; Bs[(lkb + 1) * 132 + ln] = v0.y;
            Bs[(lkb + 2) * 132 + ln] = v0.z; Bs[(lkb + 3) * 132 + ln] = v0.w;
            Bs[(lkb + 4) * 132 + ln] = v1.x; Bs[(lkb + 5) * 132 + ln] = v1.y;
            Bs[(lkb + 6) * 132 + ln] = v1.z; Bs[(lkb + 7) * 132 + ln] = v1.w;
        }
        __syncthreads();
#pragma unroll
        for (int k = 0; k < 32; ++k) {
            float4 a4 = *(const float4*)&As[k * 68 + ty * 4];
            float4 b4 = *(const float4*)&Bs[k * 132 + tx * 4];
            float av[4] = {a4.x, a4.y, a4.z, a4.w};
            float bv[4] = {b4.x, b4.y, b4.z, b4.w};
#pragma unroll
            for (int i = 0; i < 4; ++i)
#pragma unroll
                for (int j = 0; j < 4; ++j)
                    acc[i][j] = fmaf(av[i], bv[j], acc[i][j]);
        }
    }
    float bb[4];
#pragma unroll
    for (int j = 0; j < 4; ++j) {
        int n = n0 + tx * 4 + j;
        bb[j] = bih[n] + bhh[n];
    }
#pragma unroll
    for (int i = 0; i < 4; ++i) {
        size_t row = (size_t)(m0 + ty * 4 + i) * 512 + n0 + tx * 4;
        *(float4*)&C[row] = make_float4(acc[i][0] + bb[0], acc[i][1] + bb[1],
                                        acc[i][2] + bb[2], acc[i][3] + bb[3]);
    }
}

// ---------------------------------------------------------------------------
// MFMA LSTM recurrence over one t-chunk (lane-local gates, double-buffered
// fp16 hi/lo h planes, one lgkm-only barrier/step).
// ---------------------------------------------------------------------------
__device__ __forceinline__ void rec_body(const float* __restrict__ P,
                                         const float* __restrict__ Whh,
                                         float* __restrict__ S,
                                         float* __restrict__ Hout,
                                         int t0, int TC, int blk, float* sm) {
    unsigned int* hpb = (unsigned int*)sm;   // [buf][pl][16][72] dwords
#define HPROW(buf, pl, m) ((_Float16*)(hpb + ((((buf)*2 + (pl))*16 + (m)) * 72)))
    const int b0   = blk * 16;
    const int tid  = threadIdx.x;
    const int lane = tid & 63;
    const int wv   = tid >> 6;
    const int quad = lane >> 4;
    const int l15  = lane & 15;
    const int hu   = wv * 16 + l15;

    h8 bh[4][4], bl[4][4];
#pragma unroll
    for (int g = 0; g < 4; ++g) {
        int n = g * 128 + hu;
#pragma unroll
        for (int q = 0; q < 4; ++q) {
            int kb = q * 32 + quad * 8;
            const float* wp = &Whh[(size_t)n * 128 + kb];
            float4 w0 = *(const float4*)wp;
            float4 w1 = *(const float4*)(wp + 4);
            float we[8] = {w0.x, w0.y, w0.z, w0.w, w1.x, w1.y, w1.z, w1.w};
#pragma unroll
            for (int j = 0; j < 8; ++j) {
                _Float16 hi = (_Float16)we[j];
                bh[g][q][j] = hi;
                bl[g][q][j] = (_Float16)(we[j] - (float)hi);
            }
        }
    }

    float c[4];
#pragma unroll
    for (int r = 0; r < 4; ++r) {
        int m = quad * 4 + r;
        float h = S[(size_t)(b0 + m) * 128 + hu];
        c[r] = S[32768 + (size_t)(b0 + m) * 128 + hu];
        _Float16 hh = (_Float16)h;
        HPROW(0, 0, m)[hu] = hh;
        HPROW(0, 1, m)[hu] = (_Float16)(h - (float)hh);
    }
    lds_barrier();

    int off[4][4];
#pragma unroll
    for (int g = 0; g < 4; ++g)
#pragma unroll
        for (int r = 0; r < 4; ++r)
            off[g][r] = (b0 + quad * 4 + r) * TC * 512 + g * 128 + hu;

    float pc[4][4];
#pragma unroll
    for (int g = 0; g < 4; ++g)
#pragma unroll
        for (int r = 0; r < 4; ++r)
            pc[g][r] = P[off[g][r]];

    const bool wr = (Hout != nullptr);
    const float* Pn = P + 512;
    float* Ho = wr ? (Hout + (size_t)t0 * 128) : nullptr;

    for (int tl = 0; tl < TC; ++tl) {
        float pn[4][4];
#pragma unroll
        for (int g = 0; g < 4; ++g)
#pragma unroll
            for (int r = 0; r < 4; ++r)
                pn[g][r] = Pn[off[g][r]];

        const int rb = tl & 1;
        h8 ah[4], al[4];
#pragma unroll
        for (int q = 0; q < 4; ++q) {
            int hoff = 32 * q + 8 * quad;
            ah[q] = *(const h8*)&HPROW(rb, 0, l15)[hoff];
            al[q] = *(const h8*)&HPROW(rb, 1, l15)[hoff];
        }

        f32x4 acc[4];
#pragma unroll
        for (int g = 0; g < 4; ++g) {
            acc[g][0] = pc[g][0]; acc[g][1] = pc[g][1];
            acc[g][2] = pc[g][2]; acc[g][3] = pc[g][3];
        }
#pragma unroll
        for (int q = 0; q < 4; ++q) {
#pragma unroll
            for (int g = 0; g < 4; ++g) {
                acc[g] = __builtin_amdgcn_mfma_f32_16x16x32_f16(ah[q], bh[g][q], acc[g], 0, 0, 0);
                acc[g] = __builtin_amdgcn_mfma_f32_16x16x32_f16(al[q], bh[g][q], acc[g], 0, 0, 0);
                acc[g] = __builtin_amdgcn_mfma_f32_16x16x32_f16(ah[q], bl[g][q], acc[g], 0, 0, 0);
            }
        }

        const int wb = (tl + 1) & 1;
#pragma unroll
        for (int r = 0; r < 4; ++r) {
            int m = quad * 4 + r;
            float iv = fsigm(acc[0][r]);
            float fv = fsigm(acc[1][r]);
            float gv = ftanh(acc[2][r]);
            float ov = fsigm(acc[3][r]);
            c[r] = fv * c[r] + iv * gv;
            float h = ov * ftanh(c[r]);
            _Float16 hh = (_Float16)h;
            HPROW(wb, 0, m)[hu] = hh;
            HPROW(wb, 1, m)[hu] = (_Float16)(h - (float)hh);
            if (wr) Ho[((size_t)(b0 + m) * 512 + tl) * 128 + hu] = h;
            if (tl == TC - 1) {
                S[(size_t)(b0 + m) * 128 + hu] = h;
                S[32768 + (size_t)(b0 + m) * 128 + hu] = c[r];
            }
        }
        lds_barrier();

        Pn += 512;
#pragma unroll
        for (int g = 0; g < 4; ++g)
#pragma unroll
            for (int r = 0; r < 4; ++r)
                pc[g][r] = pn[g][r];
    }
#undef HPROW
}

// ---------------------------------------------------------------------------
// K5: fused pipeline stage (multi-launch). Blocks 0-15: rec0 chunk k.
// 16-31: rec1 chunk k-2. Rest: pre-gate GEMMs (pre0 k+1, pre1 k-1).
// 80 KB LDS -> 1 block/CU: rec blocks own their CUs exclusively.
// ---------------------------------------------------------------------------
__global__ __launch_bounds__(512, 1) void k_fused(
        const float* __restrict__ X,    const float* __restrict__ H0,
        const float* __restrict__ Wih0, const float* __restrict__ Wih1,
        const float* __restrict__ bih0, const float* __restrict__ bhh0,
        const float* __restrict__ bih1, const float* __restrict__ bhh1,
        const float* __restrict__ Whh0, const float* __restrict__ Whh1,
        const float* __restrict__ P0r, float* __restrict__ P0w,
        const float* __restrict__ P1r, float* __restrict__ P1w,
        float* __restrict__ S0, float* __restrict__ S1, float* __restrict__ H0out,
        int tr0, int tr1, int tp0, int tp1,
        int v_rec0, int v_rec1, int v_pre0, int v_pre1,
        int TC, int tcs) {
    __shared__ float smem[20480];   // 80 KB -> 1 block/CU (CU isolation)
    const int bid = blockIdx.x;
    if (bid < 16) {
        if (v_rec0) rec_body(P0r, Whh0, S0, H0out, tr0, TC, bid, smem);
        return;
    }
    if (bid < 32) {
        if (v_rec1) rec_body(P1r, Whh1, S1, nullptr, tr1, TC, bid - 16, smem);
        return;
    }
    int gb = bid - 32;
    const int npre = 16 * TC;
    if (gb < npre) {
        if (v_pre0) pregemm_body<64>(X, Wih0, bih0, bhh0, P0w, tp0, tcs, gb, smem);
        return;
    }
    gb -= npre;
    if (v_pre1) pregemm_body<128>(H0, Wih1, bih1, bhh1, P1w, tp1, tcs, gb, smem);
}

// ---------------------------------------------------------------------------
// K6: tail head: out = tanh(tanh(h1_last) @ W2^T + b2) @ W3^T + b3
// ---------------------------------------------------------------------------
__global__ __launch_bounds__(64) void k_tail(const float* __restrict__ Hs,
                                             const float* __restrict__ W2,
                                             const float* __restrict__ b2,
                                             const float* __restrict__ W3,
                                             const float* __restrict__ b3,
                                             float* __restrict__ out) {
    __shared__ float last[128], l2s[64];
    const int b = blockIdx.x, tid = threadIdx.x;
    last[tid]      = ftanh(Hs[(size_t)b * 128 + tid]);
    last[tid + 64] = ftanh(Hs[(size_t)b * 128 + 64 + tid]);
    __syncthreads();
    float acc = b2[tid];
#pragma unroll 4
    for (int j = 0; j < 128; ++j) acc = fmaf(W2[(size_t)tid * 128 + j], last[j], acc);
    l2s[tid] = ftanh(acc);
    __syncthreads();
    if (tid < 32) {
        float a2 = b3[tid];
#pragma unroll 4
        for (int o = 0; o < 64; ++o) a2 = fmaf(W3[(size_t)tid * 64 + o], l2s[o], a2);
        out[(size_t)b * 32 + tid] = a2;
    }
}

// ---------------------------------------------------------------------------
extern "C" void kernel_launch(void* const* d_in, const int* in_sizes, int n_in,
                              void* d_out, int out_size, void* d_ws, size_t ws_size,
                              hipStream_t stream) {
    (void)in_sizes; (void)n_in; (void)out_size;
    const float* inp  = (const float*)d_in[0];
    const float* akey = (const float*)d_in[1];
    const float* aval = (const float*)d_in[2];
    const float* W1   = (const float*)d_in[3];
    const float* b1   = (const float*)d_in[4];
    const float* Wih0 = (const float*)d_in[5];
    const float* Whh0 = (const float*)d_in[6];
    const float* bih0 = (const float*)d_in[7];
    const float* bhh0 = (const float*)d_in[8];
    const float* Wih1 = (const float*)d_in[9];
    const float* Whh1 = (const float*)d_in[10];
    const float* bih1 = (const float*)d_in[11];
    const float* bhh1 = (const float*)d_in[12];
    const float* W2   = (const float*)d_in[13];
    const float* b2   = (const float*)d_in[14];
    const float* W3   = (const float*)d_in[15];
    const float* b3   = (const float*)d_in[16];

    float* ws   = (float*)d_ws;
    float* dist = ws;                       // 2,097,152
    float* hist = dist + 2097152;           //   139,264
    float* X    = hist + 139264;            // 8,388,608 + 64 pad
    float* S0   = X + 8388672;              //    65,536 (h then c)
    float* S1   = S0 + 65536;               //    65,536
    float* H0   = S1 + 65536;               // 16,777,216  (h0, [b][512][128])
    float* PB   = H0 + 16777216;            // 4 P buffers
    const size_t fixed = (size_t)(PB - ws);

    // 4 P buffers of 256*TC*512 + 512 floats (P0 x2, P1 x2 ping-pong)
    int TC = 16, tcs = 4;
    if ((fixed + 4ull * ((size_t)256 * 32 * 512 + 512)) * 4 <= ws_size) { TC = 32; tcs = 5; }
    const size_t pchunk = (size_t)256 * TC * 512 + 512;
    float* P0b[2] = {PB, PB + pchunk};
    float* P1b[2] = {PB + 2 * pchunk, PB + 3 * pchunk};

    k_distM<<<dim3(64, 4), 256, 0, stream>>>(inp, akey, dist);
    k_softmax<<<256, 256, 0, stream>>>(dist);
    hipMemsetAsync(hist, 0, 139264 * 4, stream);
    k_histM<<<dim3(9, 4, 8), 256, 0, stream>>>(dist, aval, hist);
    k_xfeat<<<dim3(4, 256), 256, 0, stream>>>(inp, hist, W1, b1, X);
    hipMemsetAsync(S0, 0, (size_t)2 * 65536 * 4, stream);  // S0+S1 contiguous

    const int NC = 512 / TC;
    const int nblocks = 32 + 32 * TC;   // 32 rec + 16*TC pre0 + 16*TC pre1
    for (int k = -1; k <= NC + 1; ++k) {
        int v_rec0 = (k >= 0 && k < NC);
        int v_rec1 = (k >= 2 && k < NC + 2);
        int v_pre0 = (k + 1 >= 0 && k + 1 < NC);
        int v_pre1 = (k - 1 >= 0 && k - 1 < NC);
        if (!(v_rec0 | v_rec1 | v_pre0 | v_pre1)) continue;
        const float* P0r = P0b[k & 1];
        float*       P0w = P0b[(k + 1) & 1];
        const float* P1r = P1b[k & 1];
        float*       P1w = P1b[(k + 1) & 1];
        k_fused<<<nblocks, 512, 0, stream>>>(
            X, H0, Wih0, Wih1, bih0, bhh0, bih1, bhh1, Whh0, Whh1,
            P0r, P0w, P1r, P1w, S0, S1, H0,
            k * TC, (k - 2) * TC, (k + 1) * TC, (k - 1) * TC,
            v_rec0, v_rec1, v_pre0, v_pre1, TC, tcs);
    }
    k_tail<<<256, 64, 0, stream>>>(S1, W2, b2, W3, b3, (float*)d_out);
}

// Round 11
// 1254.289 us; speedup vs baseline: 3.5049x; 1.0441x over previous
//
#include <hip/hip_runtime.h>

typedef _Float16 h8 __attribute__((ext_vector_type(8)));
typedef _Float16 h4 __attribute__((ext_vector_type(4)));
typedef float f32x4 __attribute__((ext_vector_type(4)));

__device__ __forceinline__ float fsigm(float x) {
    return __builtin_amdgcn_rcpf(1.0f + __expf(-x));
}
// tanh(x) = 1 - 2/(1+e^{2x}) : no abs/copysign, inf-safe (rcp(inf)=0).
__device__ __forceinline__ float ftanh(float x) {
    return 1.0f - 2.0f * __builtin_amdgcn_rcpf(1.0f + __expf(2.0f * x));
}
// LDS-only barrier: drains lgkmcnt, leaves global loads/stores in flight.
__device__ __forceinline__ void lds_barrier() {
    asm volatile("s_waitcnt lgkmcnt(0)\n\ts_barrier" ::: "memory");
}

// ---------------------------------------------------------------------------
// K1: dist[256][8192] = input[256][512] @ akey[8192][512]^T
// MFMA f16 hi/lo. Tile 64m x 64n (512 blocks -> 2/CU for latency hiding).
// ---------------------------------------------------------------------------
__global__ __launch_bounds__(256) void k_distM(const float* __restrict__ A,
                                               const float* __restrict__ Bm,
                                               float* __restrict__ C) {
    __shared__ _Float16 Ah[64][40], Al[64][40];   // [m][k], pad 40
    __shared__ _Float16 Bh[64][40], Bl[64][40];   // [n][k]
    const int n0 = blockIdx.x * 64;
    const int m0 = blockIdx.y * 64;
    const int tid = threadIdx.x;
    const int lane = tid & 63, wv = tid >> 6;
    const int quad = lane >> 4, l15 = lane & 15;
    f32x4 acc[4];
#pragma unroll
    for (int i = 0; i < 4; ++i) acc[i] = (f32x4){0.f, 0.f, 0.f, 0.f};

    for (int kt = 0; kt < 512; kt += 32) {
        __syncthreads();
#pragma unroll
        for (int r = 0; r < 2; ++r) {           // A: 64x32 = 512 float4
            int idx = tid + 256 * r;
            int m = idx >> 3, kq = (idx & 7) * 4;
            float4 v = *(const float4*)&A[(size_t)(m0 + m) * 512 + kt + kq];
            float e[4] = {v.x, v.y, v.z, v.w};
            h4 hi, lo;
#pragma unroll
            for (int j = 0; j < 4; ++j) {
                _Float16 h = (_Float16)e[j];
                hi[j] = h; lo[j] = (_Float16)(e[j] - (float)h);
            }
            *(h4*)&Ah[m][kq] = hi;
            *(h4*)&Al[m][kq] = lo;
        }
#pragma unroll
        for (int r = 0; r < 2; ++r) {           // B: 64x32 = 512 float4
            int idx = tid + 256 * r;
            int n = idx >> 3, kq = (idx & 7) * 4;
            float4 v = *(const float4*)&Bm[(size_t)(n0 + n) * 512 + kt + kq];
            float e[4] = {v.x, v.y, v.z, v.w};
            h4 hi, lo;
#pragma unroll
            for (int j = 0; j < 4; ++j) {
                _Float16 h = (_Float16)e[j];
                hi[j] = h; lo[j] = (_Float16)(e[j] - (float)h);
            }
            *(h4*)&Bh[n][kq] = hi;
            *(h4*)&Bl[n][kq] = lo;
        }
        __syncthreads();
        h8 ah = *(const h8*)&Ah[wv * 16 + l15][quad * 8];
        h8 al = *(const h8*)&Al[wv * 16 + l15][quad * 8];
#pragma unroll
        for (int nt = 0; nt < 4; ++nt) {
            h8 bhf = *(const h8*)&Bh[nt * 16 + l15][quad * 8];
            h8 blf = *(const h8*)&Bl[nt * 16 + l15][quad * 8];
            acc[nt] = __builtin_amdgcn_mfma_f32_16x16x32_f16(ah, bhf, acc[nt], 0, 0, 0);
            acc[nt] = __builtin_amdgcn_mfma_f32_16x16x32_f16(al, bhf, acc[nt], 0, 0, 0);
            acc[nt] = __builtin_amdgcn_mfma_f32_16x16x32_f16(ah, blf, acc[nt], 0, 0, 0);
        }
    }
#pragma unroll
    for (int nt = 0; nt < 4; ++nt)
#pragma unroll
        for (int r = 0; r < 4; ++r)
            C[(size_t)(m0 + wv * 16 + quad * 4 + r) * 8192 + n0 + nt * 16 + l15] = acc[nt][r];
}

// ---------------------------------------------------------------------------
// K2: per-row argmax (first index on ties) -> set 0 -> softmax, in place.
// Single fused scan computes (max1, first idx, max2); after zeroing idx1 the
// softmax max is exactly max(max2, 0) (duplicates fold via loser.m1).
// ---------------------------------------------------------------------------
__global__ __launch_bounds__(512) void k_softmax(float* __restrict__ D) {
    __shared__ float row[8192];
    __shared__ float r1[512];
    __shared__ int   ri[512];
    __shared__ float r2[512];
    const int b = blockIdx.x, tid = threadIdx.x;
    float* dr = D + (size_t)b * 8192;
    for (int i = tid; i < 2048; i += 512)
        *(float4*)&row[i * 4] = *(const float4*)&dr[i * 4];
    __syncthreads();

    // fused (max1, idx1, max2) scan (per-thread i ascending -> first-idx kept)
    float m1 = -INFINITY, m2 = -INFINITY; int i1 = 0x7fffffff;
    for (int i = tid; i < 8192; i += 512) {
        float v = row[i];
        if (v > m1) { m2 = m1; m1 = v; i1 = i; }
        else        { m2 = fmaxf(m2, v); }       // v==m1 duplicate -> m2=m1
    }
    r1[tid] = m1; ri[tid] = i1; r2[tid] = m2;
    __syncthreads();
    for (int s = 256; s > 0; s >>= 1) {
        if (tid < s) {
            float am1 = r1[tid], bm1 = r1[tid + s];
            int   ai1 = ri[tid], bi1 = ri[tid + s];
            float am2 = r2[tid], bm2 = r2[tid + s];
            bool bwins = (bm1 > am1) || (bm1 == am1 && bi1 < ai1);
            float wm1 = bwins ? bm1 : am1;
            int   wi1 = bwins ? bi1 : ai1;
            float lm1 = bwins ? am1 : bm1;       // loser's max (covers dups)
            float wm2 = fmaxf(fmaxf(am2, bm2), lm1);
            r1[tid] = wm1; ri[tid] = wi1; r2[tid] = wm2;
        }
        __syncthreads();
    }
    const int   I1 = ri[0];
    const float M  = fmaxf(r2[0], 0.0f);          // max of modified row
    __syncthreads();

    float ssum = 0.0f;
    for (int i = tid; i < 8192; i += 512) {
        float v = (i == I1) ? 0.0f : row[i];
        float e = __expf(v - M);
        row[i] = e;
        ssum += e;
    }
    r1[tid] = ssum;
    __syncthreads();
    for (int s = 256; s > 0; s >>= 1) {
        if (tid < s) r1[tid] += r1[tid + s];
        __syncthreads();
    }
    const float inv = 1.0f / r1[0];
    for (int i = tid; i < 2048; i += 512) {
        float4 v = *(float4*)&row[i * 4];
        v.x *= inv; v.y *= inv; v.z *= inv; v.w *= inv;
        *(float4*)&dr[i * 4] = v;
    }
}

// ---------------------------------------------------------------------------
// K3: hist[256][544] += a[256][8192] @ aval[8192][544]
// MFMA f16 hi/lo, split-K=16 (576 blocks -> 2.25/CU), tile 64m x 64n.
// ---------------------------------------------------------------------------
__global__ __launch_bounds__(256) void k_histM(const float* __restrict__ A,
                                               const float* __restrict__ Bm,
                                               float* __restrict__ C) {
    __shared__ _Float16 Ah[64][40], Al[64][40];   // [m][k]
    __shared__ _Float16 Bh[64][40], Bl[64][40];   // [n][k] (transposed aval)
    const int n0 = blockIdx.x * 64;
    const int m0 = blockIdx.y * 64;
    const int kz = blockIdx.z;
    const int tid = threadIdx.x;
    const int lane = tid & 63, wv = tid >> 6;
    const int quad = lane >> 4, l15 = lane & 15;
    f32x4 acc[4];
#pragma unroll
    for (int i = 0; i < 4; ++i) acc[i] = (f32x4){0.f, 0.f, 0.f, 0.f};

    const int k_lo = kz * 512, k_hi = k_lo + 512;
    for (int kt = k_lo; kt < k_hi; kt += 32) {
        __syncthreads();
#pragma unroll
        for (int r = 0; r < 2; ++r) {           // A: 64x32 = 512 float4
            int idx = tid + 256 * r;
            int m = idx >> 3, kq = (idx & 7) * 4;
            float4 v = *(const float4*)&A[(size_t)(m0 + m) * 8192 + kt + kq];
            float e[4] = {v.x, v.y, v.z, v.w};
            h4 hi, lo;
#pragma unroll
            for (int j = 0; j < 4; ++j) {
                _Float16 h = (_Float16)e[j];
                hi[j] = h; lo[j] = (_Float16)(e[j] - (float)h);
            }
            *(h4*)&Ah[m][kq] = hi;
            *(h4*)&Al[m][kq] = lo;
        }
#pragma unroll
        for (int r = 0; r < 2; ++r) {           // B: aval[32k][64n] -> [n][k]
            int idx = tid + 256 * r;
            int kk = idx >> 4;                  // 0..31
            int nq = (idx & 15) * 4;            // 0..60
            float4 v = make_float4(0.f, 0.f, 0.f, 0.f);
            if (n0 + nq < 544)
                v = *(const float4*)&Bm[(size_t)(kt + kk) * 544 + n0 + nq];
            float e[4] = {v.x, v.y, v.z, v.w};
#pragma unroll
            for (int j = 0; j < 4; ++j) {
                _Float16 h = (_Float16)e[j];
                Bh[nq + j][kk] = h;
                Bl[nq + j][kk] = (_Float16)(e[j] - (float)h);
            }
        }
        __syncthreads();
        h8 ah = *(const h8*)&Ah[wv * 16 + l15][quad * 8];
        h8 al = *(const h8*)&Al[wv * 16 + l15][quad * 8];
#pragma unroll
        for (int nt = 0; nt < 4; ++nt) {
            h8 bhf = *(const h8*)&Bh[nt * 16 + l15][quad * 8];
            h8 blf = *(const h8*)&Bl[nt * 16 + l15][quad * 8];
            acc[nt] = __builtin_amdgcn_mfma_f32_16x16x32_f16(ah, bhf, acc[nt], 0, 0, 0);
            acc[nt] = __builtin_amdgcn_mfma_f32_16x16x32_f16(al, bhf, acc[nt], 0, 0, 0);
            acc[nt] = __builtin_amdgcn_mfma_f32_16x16x32_f16(ah, blf, acc[nt], 0, 0, 0);
        }
    }
#pragma unroll
    for (int nt = 0; nt < 4; ++nt)
#pragma unroll
        for (int r = 0; r < 4; ++r) {
            int n = n0 + nt * 16 + l15;
            if (n < 544)
                atomicAdd(&C[(size_t)(m0 + wv * 16 + quad * 4 + r) * 544 + n], acc[nt][r]);
        }
}

// ---------------------------------------------------------------------------
// K4: x[b][t][o] = tanh(b1[o] + W1[o][0]*input[b][t] + sum_j W1[o][1+j]*hist[b][t+j])
// ---------------------------------------------------------------------------
__global__ __launch_bounds__(256) void k_xfeat(const float* __restrict__ inp,
                                               const float* __restrict__ hist,
                                               const float* __restrict__ W1,
                                               const float* __restrict__ b1,
                                               float* __restrict__ X) {
    __shared__ float w[33 * 64];
    __shared__ float bl[64];
    __shared__ float il[128];
    __shared__ float hl[160];
    const int t0 = blockIdx.x * 128;
    const int b  = blockIdx.y;
    const int tid = threadIdx.x;
    for (int idx = tid; idx < 2112; idx += 256) {
        int o = idx / 33, k = idx % 33;
        w[k * 64 + o] = W1[idx];
    }
    if (tid < 64) bl[tid] = b1[tid];
    if (tid < 128) il[tid] = inp[(size_t)b * 512 + t0 + tid];
    for (int i = tid; i < 159; i += 256) hl[i] = hist[(size_t)b * 544 + t0 + i];
    __syncthreads();
    const int o = tid & 63, tq = tid >> 6;
    for (int it = 0; it < 32; ++it) {
        int tl = it * 4 + tq;
        float acc = fmaf(il[tl], w[o], bl[o]);
#pragma unroll
        for (int j = 0; j < 32; ++j)
            acc = fmaf(hl[tl + j], w[(1 + j) * 64 + o], acc);
        X[(size_t)(b * 512 + t0 + tl) * 64 + o] = ftanh(acc);
    }
}

// ---------------------------------------------------------------------------
// Pre-gate GEMM body, 512 threads, tile 64(m) x 128(n) x 32(k).
// ---------------------------------------------------------------------------
template <int K>
__device__ __forceinline__ void pregemm_body(const float* __restrict__ A,
                                             const float* __restrict__ Bw,
                                             const float* __restrict__ bih,
                                             const float* __restrict__ bhh,
                                             float* __restrict__ C,
                                             int t0, int tcs, int gb, float* sm) {
    float* As = sm;             // [32][68]
    float* Bs = sm + 32 * 68;   // [32][132]
    const int n0 = (gb & 3) * 128;
    const int m0 = (gb >> 2) * 64;
    const int tid = threadIdx.x;
    const int tx = tid & 31;
    const int ty = tid >> 5;
    const int lm = tid >> 3;
    const int lk = (tid & 7) * 4;
    const int ln = tid >> 2;
    const int lkb = (tid & 3) * 8;
    const int tcm = (1 << tcs) - 1;
    float acc[4][4];
#pragma unroll
    for (int i = 0; i < 4; ++i)
#pragma unroll
        for (int j = 0; j < 4; ++j) acc[i][j] = 0.0f;

    for (int kt = 0; kt < K; kt += 32) {
        __syncthreads();
        {
            int m = m0 + lm;
            size_t arow = (size_t)(m >> tcs) * 512 + t0 + (m & tcm);
            float4 v = *(const float4*)&A[arow * K + kt + lk];
            As[(lk + 0) * 68 + lm] = v.x; As[(lk + 1) * 68 + lm] = v.y;
            As[(lk + 2) * 68 + lm] = v.z; As[(lk + 3) * 68 + lm] = v.w;
        }
        {
            const float* bp = &Bw[(size_t)(n0 + ln) * K + kt + lkb];
            float4 v0 = *(const float4*)bp;
            float4 v1 = *(const float4*)(bp + 4);
            Bs[(lkb + 0) * 132 + ln] = v0.x; Bs[(lkb + 1) * 132 + ln] = v0.y;
            Bs[(lkb + 2) * 132 + ln] = v0.z; Bs[(lkb + 3) * 132 + ln] = v0.w;
            Bs[(lkb + 4) * 132 + ln] = v1.x; Bs[(lkb + 5) * 132 + ln] = v1.y;
            Bs[(lkb + 6) * 132 + ln] = v1.z; Bs[(lkb + 7) * 132 + ln] = v1.w;
        }
        __syncthreads();
#pragma unroll
        for (int k = 0; k < 32; ++k) {
            float4 a4 = *(const float4*)&As[k * 68 + ty * 4];
            float4 b4 = *(const float4*)&Bs[k * 132 + tx * 4];
            float av[4] = {a4.x, a4.y, a4.z, a4.w};
            float bv[4] = {b4.x, b4.y, b4.z, b4.w};
#pragma unroll
            for (int i = 0; i < 4; ++i)
#pragma unroll
                for (int j = 0; j < 4; ++j)
                    acc[i][j] = fmaf(av[i], bv[j], acc[i][j]);
        }
    }
    float bb[4];
#pragma unroll
    for (int j = 0; j < 4; ++j) {
        int n = n0 + tx * 4 + j;
        bb[j] = bih[n] + bhh[n];
    }
#pragma unroll
    for (int i = 0; i < 4; ++i) {
        size_t row = (size_t)(m0 + ty * 4 + i) * 512 + n0 + tx * 4;
        *(float4*)&C[row] = make_float4(acc[i][0] + bb[0], acc[i][1] + bb[1],
                                        acc[i][2] + bb[2], acc[i][3] + bb[3]);
    }
}

// ---------------------------------------------------------------------------
// MFMA LSTM recurrence over one t-chunk (lane-local gates, double-buffered
// fp16 hi/lo h planes, one lgkm-only barrier/step).
// ---------------------------------------------------------------------------
__device__ __forceinline__ void rec_body(const float* __restrict__ P,
                                         const float* __restrict__ Whh,
                                         float* __restrict__ S,
                                         float* __restrict__ Hout,
                                         int t0, int TC, int blk, float* sm) {
    unsigned int* hpb = (unsigned int*)sm;   // [buf][pl][16][72] dwords
#define HPROW(buf, pl, m) ((_Float16*)(hpb + ((((buf)*2 + (pl))*16 + (m)) * 72)))
    const int b0   = blk * 16;
    const int tid  = threadIdx.x;
    const int lane = tid & 63;
    const int wv   = tid >> 6;
    const int quad = lane >> 4;
    const int l15  = lane & 15;
    const int hu   = wv * 16 + l15;

    h8 bh[4][4], bl[4][4];
#pragma unroll
    for (int g = 0; g < 4; ++g) {
        int n = g * 128 + hu;
#pragma unroll
        for (int q = 0; q < 4; ++q) {
            int kb = q * 32 + quad * 8;
            const float* wp = &Whh[(size_t)n * 128 + kb];
            float4 w0 = *(const float4*)wp;
            float4 w1 = *(const float4*)(wp + 4);
            float we[8] = {w0.x, w0.y, w0.z, w0.w, w1.x, w1.y, w1.z, w1.w};
#pragma unroll
            for (int j = 0; j < 8; ++j) {
                _Float16 hi = (_Float16)we[j];
                bh[g][q][j] = hi;
                bl[g][q][j] = (_Float16)(we[j] - (float)hi);
            }
        }
    }

    float c[4];
#pragma unroll
    for (int r = 0; r < 4; ++r) {
        int m = quad * 4 + r;
        float h = S[(size_t)(b0 + m) * 128 + hu];
        c[r] = S[32768 + (size_t)(b0 + m) * 128 + hu];
        _Float16 hh = (_Float16)h;
        HPROW(0, 0, m)[hu] = hh;
        HPROW(0, 1, m)[hu] = (_Float16)(h - (float)hh);
    }
    lds_barrier();

    int off[4][4];
#pragma unroll
    for (int g = 0; g < 4; ++g)
#pragma unroll
        for (int r = 0; r < 4; ++r)
            off[g][r] = (b0 + quad * 4 + r) * TC * 512 + g * 128 + hu;

    float pc[4][4];
#pragma unroll
    for (int g = 0; g < 4; ++g)
#pragma unroll
        for (int r = 0; r < 4; ++r)
            pc[g][r] = P[off[g][r]];

    const bool wr = (Hout != nullptr);
    const float* Pn = P + 512;
    float* Ho = wr ? (Hout + (size_t)t0 * 128) : nullptr;

    for (int tl = 0; tl < TC; ++tl) {
        float pn[4][4];
#pragma unroll
        for (int g = 0; g < 4; ++g)
#pragma unroll
            for (int r = 0; r < 4; ++r)
                pn[g][r] = Pn[off[g][r]];

        const int rb = tl & 1;
        h8 ah[4], al[4];
#pragma unroll
        for (int q = 0; q < 4; ++q) {
            int hoff = 32 * q + 8 * quad;
            ah[q] = *(const h8*)&HPROW(rb, 0, l15)[hoff];
            al[q] = *(const h8*)&HPROW(rb, 1, l15)[hoff];
        }

        f32x4 acc[4];
#pragma unroll
        for (int g = 0; g < 4; ++g) {
            acc[g][0] = pc[g][0]; acc[g][1] = pc[g][1];
            acc[g][2] = pc[g][2]; acc[g][3] = pc[g][3];
        }
#pragma unroll
        for (int q = 0; q < 4; ++q) {
#pragma unroll
            for (int g = 0; g < 4; ++g) {
                acc[g] = __builtin_amdgcn_mfma_f32_16x16x32_f16(ah[q], bh[g][q], acc[g], 0, 0, 0);
                acc[g] = __builtin_amdgcn_mfma_f32_16x16x32_f16(al[q], bh[g][q], acc[g], 0, 0, 0);
                acc[g] = __builtin_amdgcn_mfma_f32_16x16x32_f16(ah[q], bl[g][q], acc[g], 0, 0, 0);
            }
        }

        const int wb = (tl + 1) & 1;
#pragma unroll
        for (int r = 0; r < 4; ++r) {
            int m = quad * 4 + r;
            float iv = fsigm(acc[0][r]);
            float fv = fsigm(acc[1][r]);
            float gv = ftanh(acc[2][r]);
            float ov = fsigm(acc[3][r]);
            c[r] = fv * c[r] + iv * gv;
            float h = ov * ftanh(c[r]);
            _Float16 hh = (_Float16)h;
            HPROW(wb, 0, m)[hu] = hh;
            HPROW(wb, 1, m)[hu] = (_Float16)(h - (float)hh);
            if (wr) Ho[((size_t)(b0 + m) * 512 + tl) * 128 + hu] = h;
            if (tl == TC - 1) {
                S[(size_t)(b0 + m) * 128 + hu] = h;
                S[32768 + (size_t)(b0 + m) * 128 + hu] = c[r];
            }
        }
        lds_barrier();

        Pn += 512;
#pragma unroll
        for (int g = 0; g < 4; ++g)
#pragma unroll
            for (int r = 0; r < 4; ++r)
                pc[g][r] = pn[g][r];
    }
#undef HPROW
}

// ---------------------------------------------------------------------------
// K5: fused pipeline stage (multi-launch). Blocks 0-15: rec0 chunk k.
// 16-31: rec1 chunk k-2. Rest: pre-gate GEMMs (pre0 k+1, pre1 k-1).
// 80 KB LDS -> 1 block/CU: rec blocks own their CUs exclusively.
// ---------------------------------------------------------------------------
__global__ __launch_bounds__(512, 1) void k_fused(
        const float* __restrict__ X,    const float* __restrict__ H0,
        const float* __restrict__ Wih0, const float* __restrict__ Wih1,
        const float* __restrict__ bih0, const float* __restrict__ bhh0,
        const float* __restrict__ bih1, const float* __restrict__ bhh1,
        const float* __restrict__ Whh0, const float* __restrict__ Whh1,
        const float* __restrict__ P0r, float* __restrict__ P0w,
        const float* __restrict__ P1r, float* __restrict__ P1w,
        float* __restrict__ S0, float* __restrict__ S1, float* __restrict__ H0out,
        int tr0, int tr1, int tp0, int tp1,
        int v_rec0, int v_rec1, int v_pre0, int v_pre1,
        int TC, int tcs) {
    __shared__ float smem[20480];   // 80 KB -> 1 block/CU (CU isolation)
    const int bid = blockIdx.x;
    if (bid < 16) {
        if (v_rec0) rec_body(P0r, Whh0, S0, H0out, tr0, TC, bid, smem);
        return;
    }
    if (bid < 32) {
        if (v_rec1) rec_body(P1r, Whh1, S1, nullptr, tr1, TC, bid - 16, smem);
        return;
    }
    int gb = bid - 32;
    const int npre = 16 * TC;
    if (gb < npre) {
        if (v_pre0) pregemm_body<64>(X, Wih0, bih0, bhh0, P0w, tp0, tcs, gb, smem);
        return;
    }
    gb -= npre;
    if (v_pre1) pregemm_body<128>(H0, Wih1, bih1, bhh1, P1w, tp1, tcs, gb, smem);
}

// ---------------------------------------------------------------------------
// K6: tail head: out = tanh(tanh(h1_last) @ W2^T + b2) @ W3^T + b3
// ---------------------------------------------------------------------------
__global__ __launch_bounds__(64) void k_tail(const float* __restrict__ Hs,
                                             const float* __restrict__ W2,
                                             const float* __restrict__ b2,
                                             const float* __restrict__ W3,
                                             const float* __restrict__ b3,
                                             float* __restrict__ out) {
    __shared__ float last[128], l2s[64];
    const int b = blockIdx.x, tid = threadIdx.x;
    last[tid]      = ftanh(Hs[(size_t)b * 128 + tid]);
    last[tid + 64] = ftanh(Hs[(size_t)b * 128 + 64 + tid]);
    __syncthreads();
    float acc = b2[tid];
#pragma unroll 4
    for (int j = 0; j < 128; ++j) acc = fmaf(W2[(size_t)tid * 128 + j], last[j], acc);
    l2s[tid] = ftanh(acc);
    __syncthreads();
    if (tid < 32) {
        float a2 = b3[tid];
#pragma unroll 4
        for (int o = 0; o < 64; ++o) a2 = fmaf(W3[(size_t)tid * 64 + o], l2s[o], a2);
        out[(size_t)b * 32 + tid] = a2;
    }
}

// ---------------------------------------------------------------------------
extern "C" void kernel_launch(void* const* d_in, const int* in_sizes, int n_in,
                              void* d_out, int out_size, void* d_ws, size_t ws_size,
                              hipStream_t stream) {
    (void)in_sizes; (void)n_in; (void)out_size;
    const float* inp  = (const float*)d_in[0];
    const float* akey = (const float*)d_in[1];
    const float* aval = (const float*)d_in[2];
    const float* W1   = (const float*)d_in[3];
    const float* b1   = (const float*)d_in[4];
    const float* Wih0 = (const float*)d_in[5];
    const float* Whh0 = (const float*)d_in[6];
    const float* bih0 = (const float*)d_in[7];
    const float* bhh0 = (const float*)d_in[8];
    const float* Wih1 = (const float*)d_in[9];
    const float* Whh1 = (const float*)d_in[10];
    const float* bih1 = (const float*)d_in[11];
    const float* bhh1 = (const float*)d_in[12];
    const float* W2   = (const float*)d_in[13];
    const float* b2   = (const float*)d_in[14];
    const float* W3   = (const float*)d_in[15];
    const float* b3   = (const float*)d_in[16];

    float* ws   = (float*)d_ws;
    float* dist = ws;                       // 2,097,152
    float* hist = dist + 2097152;           //   139,264
    float* X    = hist + 139264;            // 8,388,608 + 64 pad
    float* S0   = X + 8388672;              //    65,536 (h then c)
    float* S1   = S0 + 65536;               //    65,536
    float* H0   = S1 + 65536;               // 16,777,216  (h0, [b][512][128])
    float* PB   = H0 + 16777216;            // 4 P buffers
    const size_t fixed = (size_t)(PB - ws);

    // 4 P buffers of 256*TC*512 + 512 floats (P0 x2, P1 x2 ping-pong)
    int TC = 16, tcs = 4;
    if ((fixed + 4ull * ((size_t)256 * 32 * 512 + 512)) * 4 <= ws_size) { TC = 32; tcs = 5; }
    const size_t pchunk = (size_t)256 * TC * 512 + 512;
    float* P0b[2] = {PB, PB + pchunk};
    float* P1b[2] = {PB + 2 * pchunk, PB + 3 * pchunk};

    k_distM<<<dim3(128, 4), 256, 0, stream>>>(inp, akey, dist);
    k_softmax<<<256, 512, 0, stream>>>(dist);
    hipMemsetAsync(hist, 0, 139264 * 4, stream);
    k_histM<<<dim3(9, 4, 16), 256, 0, stream>>>(dist, aval, hist);
    k_xfeat<<<dim3(4, 256), 256, 0, stream>>>(inp, hist, W1, b1, X);
    hipMemsetAsync(S0, 0, (size_t)2 * 65536 * 4, stream);  // S0+S1 contiguous

    const int NC = 512 / TC;
    const int nblocks = 32 + 32 * TC;   // 32 rec + 16*TC pre0 + 16*TC pre1
    for (int k = -1; k <= NC + 1; ++k) {
        int v_rec0 = (k >= 0 && k < NC);
        int v_rec1 = (k >= 2 && k < NC + 2);
        int v_pre0 = (k + 1 >= 0 && k + 1 < NC);
        int v_pre1 = (k - 1 >= 0 && k - 1 < NC);
        if (!(v_rec0 | v_rec1 | v_pre0 | v_pre1)) continue;
        const float* P0r = P0b[k & 1];
        float*       P0w = P0b[(k + 1) & 1];
        const float* P1r = P1b[k & 1];
        float*       P1w = P1b[(k + 1) & 1];
        k_fused<<<nblocks, 512, 0, stream>>>(
            X, H0, Wih0, Wih1, bih0, bhh0, bih1, bhh1, Whh0, Whh1,
            P0r, P0w, P1r, P1w, S0, S1, H0,
            k * TC, (k - 2) * TC, (k + 1) * TC, (k - 1) * TC,
            v_rec0, v_rec1, v_pre0, v_pre1, TC, tcs);
    }
    k_tail<<<256, 64, 0, stream>>>(S1, W2, b2, W3, b3, (float*)d_out);
}